// Round 4
// baseline (212.714 us; speedup 1.0000x reference)
//
#include <hip/hip_runtime.h>
#include <hip/hip_bf16.h>
#include <math.h>

// Problem constants (B=8, T=1024, EMB=768, H=12, D=64)
#define BATCH 8
#define SEQ   1024
#define EMB   768
#define NH    12
#define HD    64
#define QKVW  (3 * EMB)   // 2304
#define VOFF  (2 * EMB)   // 1536 — start of V columns in qkv

typedef short short8   __attribute__((ext_vector_type(8)));
typedef float floatx4  __attribute__((ext_vector_type(4)));

// fp32 -> bf16 (RNE) as raw short
__device__ __forceinline__ short f2bf(float f) {
    union { float f; unsigned u; } v; v.f = f;
    unsigned r = (v.u + 0x7fffu + ((v.u >> 16) & 1u)) >> 16;
    return (short)r;
}

// async 16B global -> LDS (wave-uniform base + lane*16 on the LDS side)
__device__ __forceinline__ void async_load16(const void* g, void* l) {
    __builtin_amdgcn_global_load_lds(
        (const __attribute__((address_space(1))) unsigned int*)g,
        (__attribute__((address_space(3))) unsigned int*)l, 16, 0, 0);
}

// ---------------------------------------------------------------------------
// fp32 -> bf16 elementwise (8 elems/thread)
// ---------------------------------------------------------------------------
__global__ __launch_bounds__(256) void cvt_bf16(
    const float* __restrict__ in, short* __restrict__ out, int n8)
{
    const int i = blockIdx.x * 256 + threadIdx.x;
    if (i >= n8) return;
    const float4 a = ((const float4*)in)[2 * i];
    const float4 b = ((const float4*)in)[2 * i + 1];
    short8 s;
    s[0] = f2bf(a.x); s[1] = f2bf(a.y); s[2] = f2bf(a.z); s[3] = f2bf(a.w);
    s[4] = f2bf(b.x); s[5] = f2bf(b.y); s[6] = f2bf(b.z); s[7] = f2bf(b.w);
    ((short8*)out)[i] = s;
}

// ---------------------------------------------------------------------------
// fp32 [R,C] -> bf16 [C,R] (transpose). R,C multiples of 32. Block 256 = 32x8.
// ---------------------------------------------------------------------------
__global__ __launch_bounds__(256) void transpose_to_bf16(
    const float* __restrict__ in, short* __restrict__ outT, int R, int C)
{
    __shared__ float t[32][33];
    const int c0 = blockIdx.x * 32, r0 = blockIdx.y * 32;
    const int lx = threadIdx.x & 31, ly = threadIdx.x >> 5;
    #pragma unroll
    for (int i = 0; i < 32; i += 8)
        t[ly + i][lx] = in[(size_t)(r0 + ly + i) * C + c0 + lx];
    __syncthreads();
    #pragma unroll
    for (int i = 0; i < 32; i += 8)
        outT[(size_t)(c0 + ly + i) * R + r0 + lx] = f2bf(t[lx][ly + i]);
}

// ---------------------------------------------------------------------------
// Shared schedule macros
// ---------------------------------------------------------------------------
#define NT12 (EMB / 64)   // 12 K-tiles

#define BAR()    do { asm volatile("" ::: "memory"); __builtin_amdgcn_s_barrier(); \
                      asm volatile("" ::: "memory"); } while (0)
#define LGKM0()  asm volatile("s_waitcnt lgkmcnt(0)" ::: "memory")
#define VMC0()   asm volatile("s_waitcnt vmcnt(0)" ::: "memory")
#define VMC4()   asm volatile("s_waitcnt vmcnt(4)" ::: "memory")
#define VMC8()   asm volatile("s_waitcnt vmcnt(8)" ::: "memory")
#define SCHED0() __builtin_amdgcn_sched_barrier(0)
#define PRIO1()  __builtin_amdgcn_s_setprio(1)
#define PRIO0()  __builtin_amdgcn_s_setprio(0)

// ---------------------------------------------------------------------------
// QKV GEMM, 256x256 tile / BK=64 / 8 waves (2Mx4N), 4-phase-per-K-tile
// schedule with DEEP staging lead (round-2 verified, 63.3 us):
//   buffer release points: B halves last read at P2, A halves at P3 ->
//   tile kt+2's B staged at P3 of kt, A at P4 of kt. The vmcnt(8) at
//   P4-end of kt keeps only tile kt+2's 8 loads in flight and guarantees
//   tile kt+1 (issued during kt-1, 4-5 phases ago) is complete — every
//   waited-on load has ~4 phases of latency hiding.
// vpath (operand order) hoisted to ONE uniform top-level branch; MFMA
// clusters kk-outer (8 independent accumulators between dependent pairs).
// ---------------------------------------------------------------------------

// swizzled fragment read: logical k-chunk q of row r lives at physical chunk q^(r&7)
#define LDA(bf_, r_, q_) (*(const short8*)&As[bf_][(r_) * 64 + ((((q_)) ^ ((r_) & 7)) << 3)])
#define LDB(bf_, r_, q_) (*(const short8*)&Bs[bf_][(r_) * 64 + ((((q_)) ^ ((r_) & 7)) << 3)])

// 16 MFMAs: acc[IB..IB+3][JB..JB+1], kk-outer for 8-wide independence.
// _T: trans path (C^T accumulate, mfma(b,a)); _D: direct (mfma(a,b)).
#define MMA_T(IB, JB)                                                        \
    _Pragma("unroll")                                                        \
    for (int kk = 0; kk < 2; ++kk)                                           \
        _Pragma("unroll")                                                    \
        for (int mi = 0; mi < 4; ++mi)                                       \
            _Pragma("unroll")                                                \
            for (int nj = 0; nj < 2; ++nj)                                   \
                acc[(IB) + mi][(JB) + nj] =                                  \
                    __builtin_amdgcn_mfma_f32_16x16x32_bf16(                 \
                        b[(JB) + nj][kk], a[mi][kk],                         \
                        acc[(IB) + mi][(JB) + nj], 0, 0, 0);

#define MMA_D(IB, JB)                                                        \
    _Pragma("unroll")                                                        \
    for (int kk = 0; kk < 2; ++kk)                                           \
        _Pragma("unroll")                                                    \
        for (int mi = 0; mi < 4; ++mi)                                       \
            _Pragma("unroll")                                                \
            for (int nj = 0; nj < 2; ++nj)                                   \
                acc[(IB) + mi][(JB) + nj] =                                  \
                    __builtin_amdgcn_mfma_f32_16x16x32_bf16(                 \
                        a[mi][kk], b[(JB) + nj][kk],                         \
                        acc[(IB) + mi][(JB) + nj], 0, 0, 0);

// One K-tile iteration loop, parameterized on the MFMA macro (uniform path).
#define KLOOP(MM)                                                            \
    for (int kt = 0; kt < NT12; ++kt) {                                      \
        const int buf = kt & 1;                                              \
        /* ---- phase 1: a lower half + b01 (12 ds_reads) ---- */            \
        _Pragma("unroll")                                                    \
        for (int mi = 0; mi < 4; ++mi)                                       \
            _Pragma("unroll")                                                \
            for (int kk = 0; kk < 2; ++kk)                                   \
                a[mi][kk] = LDA(buf, ar0 + mi * 16, quad + kk * 4);          \
        _Pragma("unroll")                                                    \
        for (int nj = 0; nj < 2; ++nj)                                       \
            _Pragma("unroll")                                                \
            for (int kk = 0; kk < 2; ++kk)                                   \
                b[nj][kk] = LDB(buf, br0 + nj * 16, quad + kk * 4);          \
        BAR(); LGKM0(); SCHED0();                                            \
        PRIO1(); MM(0, 0); PRIO0();                                          \
        BAR();                                                               \
        /* ---- phase 2: b23 (4 ds_reads) ---- */                            \
        _Pragma("unroll")                                                    \
        for (int nj = 2; nj < 4; ++nj)                                       \
            _Pragma("unroll")                                                \
            for (int kk = 0; kk < 2; ++kk)                                   \
                b[nj][kk] = LDB(buf, br0 + nj * 16, quad + kk * 4);          \
        BAR(); LGKM0(); SCHED0();                                            \
        PRIO1(); MM(0, 2); PRIO0();                                          \
        BAR();                                                               \
        /* ---- phase 3: a upper half (8 ds_reads); stage kt+2 B ---- */     \
        _Pragma("unroll")                                                    \
        for (int mi = 0; mi < 4; ++mi)                                       \
            _Pragma("unroll")                                                \
            for (int kk = 0; kk < 2; ++kk)                                   \
                a[mi][kk] = LDA(buf, ar0 + 64 + mi * 16, quad + kk * 4);     \
        stage_half(kt + 2, 2); stage_half(kt + 2, 3);                        \
        BAR(); LGKM0(); SCHED0();                                            \
        PRIO1(); MM(4, 2); PRIO0();                                          \
        BAR();                                                               \
        /* ---- phase 4: no ds_reads; stage kt+2 A ---- */                   \
        stage_half(kt + 2, 0); stage_half(kt + 2, 1);                        \
        SCHED0();                                                            \
        PRIO1(); MM(4, 0); PRIO0();                                          \
        if (kt + 2 < NT12) { VMC8(); } else { VMC0(); }                      \
        BAR();                                                               \
    }

__global__ __launch_bounds__(512, 2) void gemm_qkv_256(
    const short* __restrict__ A, const short* __restrict__ Bt,
    const float* __restrict__ bias, short* __restrict__ qkvb,
    short* __restrict__ vt)
{
    __shared__ __align__(16) short As[2][256 * 64];   // 64 KB (2 K-tile buffers)
    __shared__ __align__(16) short Bs[2][256 * 64];   // 64 KB

    const int tid  = threadIdx.x;
    const int wave = tid >> 6;
    const int lane = tid & 63;
    const int ln15 = lane & 15;
    const int quad = lane >> 4;
    const int wm   = wave >> 2;        // 0..1  (M direction, 128 rows each)
    const int wn   = wave & 3;         // 0..3  (N direction, 64 cols each)

    // XCD-bijective swizzle: 288 blocks, 36 consecutive tiles per XCD
    const int orig = blockIdx.x;
    const int wg   = (orig & 7) * 36 + (orig >> 3);
    const int bx   = wg % (QKVW / 256);   // 0..8
    const int by   = wg / (QKVW / 256);   // 0..31
    const int row0 = by * 256;
    const int col0 = bx * 256;
    const bool vpath = (col0 >= VOFF);    // tiles 6,7,8 are the V columns

    const short* Ag = A  + (size_t)row0 * EMB;
    const short* Bg = Bt + (size_t)col0 * EMB;

    // stage one half-tile of K-tile t: h = 0 (A rows 0-127), 1 (A 128-255),
    // 2 (B rows 0-127), 3 (B 128-255). 2 global_load_lds per wave per call.
    auto stage_half = [&](int t, int h) {
        if (t >= NT12) return;
        const int buf   = t & 1;
        const int k0    = t * 64;
        const int rbase = (h & 1) * 128;
        short* lb       = (h < 2) ? &As[buf][rbase * 64] : &Bs[buf][rbase * 64];
        const short* gb = (h < 2) ? Ag : Bg;
        #pragma unroll
        for (int p = 0; p < 2; ++p) {
            const int id  = p * 512 + tid;        // 0..1023
            const int row = rbase + (id >> 3);    // 0..255
            const int c   = (id & 7) ^ (row & 7); // pre-swizzled source chunk
            async_load16(gb + (size_t)row * EMB + k0 + c * 8, lb + (size_t)id * 8);
        }
    };

    floatx4 acc[8][4];
    #pragma unroll
    for (int i = 0; i < 8; ++i)
        #pragma unroll
        for (int j = 0; j < 4; ++j) acc[i][j] = (floatx4){0.f, 0.f, 0.f, 0.f};

    short8 a[4][2];   // current M-half A fragments
    short8 b[4][2];   // all four N fragments (live across phases)

    // ---- prologue: fully stage tiles 0 and 1 (8 loads each per wave) ----
    #pragma unroll
    for (int h = 0; h < 4; ++h) stage_half(0, h);
    #pragma unroll
    for (int h = 0; h < 4; ++h) stage_half(1, h);
    VMC8();           // tile 0 complete; tile 1's 8 loads stay in flight
    BAR();

    const int ar0 = wm * 128 + ln15;
    const int br0 = wn * 64 + ln15;

    if (vpath) { KLOOP(MMA_D) } else { KLOOP(MMA_T) }

    // ---- epilogue (same per-16x16 conventions as the verified 128^2 kernel) ----
    if (!vpath) {
        // trans acc: lane holds row r = ...+ln15, cols c = ...+quad*4+reg
        #pragma unroll
        for (int j = 0; j < 4; ++j) {
            const float4 b4 = *(const float4*)&bias[col0 + wn * 64 + j * 16 + quad * 4];
            #pragma unroll
            for (int i = 0; i < 8; ++i) {
                const int r = row0 + wm * 128 + i * 16 + ln15;
                const int c = col0 + wn * 64 + j * 16 + quad * 4;
                union { short s[4]; unsigned long long u; } pk;
                pk.s[0] = f2bf(acc[i][j][0] + b4.x);
                pk.s[1] = f2bf(acc[i][j][1] + b4.y);
                pk.s[2] = f2bf(acc[i][j][2] + b4.z);
                pk.s[3] = f2bf(acc[i][j][3] + b4.w);
                *(unsigned long long*)&qkvb[(size_t)r * QKVW + c] = pk.u;
            }
        }
    } else {
        // direct acc: lane holds col c = ...+ln15, rows r = ...+quad*4+reg
        #pragma unroll
        for (int j = 0; j < 4; ++j) {
            const int c  = col0 + wn * 64 + j * 16 + ln15;
            const float bv = bias[c];
            const int c2 = c - VOFF;
            #pragma unroll
            for (int i = 0; i < 8; ++i) {
                const int r = row0 + wm * 128 + i * 16 + quad * 4;
                union { short s[4]; unsigned long long u; } pk;
                #pragma unroll
                for (int reg = 0; reg < 4; ++reg)
                    pk.s[reg] = f2bf(acc[i][j][reg] + bv);
                *(unsigned long long*)&vt[(size_t)(r >> 10) * (EMB * SEQ) +
                                          (size_t)c2 * SEQ + (r & 1023)] = pk.u;
            }
        }
    }
}

// ---------------------------------------------------------------------------
// Proj GEMM: 128x192 tile / BK=64 / 6 waves (2M x 3N), per-wave 64x64.
// LDS = 80 KiB -> 2 blocks/CU; grid 256 (fully resident, single round) —
// the packing regime where this shape measured a ~23 us win (round 3).
// MODE 0 only here (fp32 out + b_proj).
// ---------------------------------------------------------------------------

// swizzled fragment read (separate names to avoid macro collision)
#define LDA8(bf_, r_, q_) (*(const short8*)&As[bf_][(r_) * 64 + ((((q_)) ^ ((r_) & 7)) << 3)])
#define LDB8(bf_, r_, q_) (*(const short8*)&Bs[bf_][(r_) * 64 + ((((q_)) ^ ((r_) & 7)) << 3)])

#define MMA_T2(JB)                                                           \
    _Pragma("unroll")                                                        \
    for (int kk = 0; kk < 2; ++kk)                                           \
        _Pragma("unroll")                                                    \
        for (int mi = 0; mi < 4; ++mi)                                       \
            _Pragma("unroll")                                                \
            for (int nj = 0; nj < 2; ++nj)                                   \
                acc[mi][(JB) + nj] =                                         \
                    __builtin_amdgcn_mfma_f32_16x16x32_bf16(                 \
                        b[(JB) + nj][kk], a[mi][kk],                         \
                        acc[mi][(JB) + nj], 0, 0, 0);

#define KLOOP2(MM)                                                           \
    for (int kt = 0; kt < NT12; ++kt) {                                      \
        const int buf = kt & 1;                                              \
        /* ---- P1: all A frags (8) + b01 (4); stage B(kt+1) ---- */         \
        _Pragma("unroll")                                                    \
        for (int mi = 0; mi < 4; ++mi)                                       \
            _Pragma("unroll")                                                \
            for (int kk = 0; kk < 2; ++kk)                                   \
                a[mi][kk] = LDA8(buf, ar0 + mi * 16, quad + kk * 4);         \
        _Pragma("unroll")                                                    \
        for (int nj = 0; nj < 2; ++nj)                                       \
            _Pragma("unroll")                                                \
            for (int kk = 0; kk < 2; ++kk)                                   \
                b[nj][kk] = LDB8(buf, br0 + nj * 16, quad + kk * 4);         \
        if (kt + 1 < NT12) stage_B(kt + 1);                                  \
        BAR(); LGKM0(); SCHED0();                                            \
        PRIO1(); MM(0); PRIO0();                                             \
        BAR();                                                               \
        /* ---- P2: b23 (4); stage A(kt+2); counted wait ---- */             \
        _Pragma("unroll")                                                    \
        for (int nj = 2; nj < 4; ++nj)                                       \
            _Pragma("unroll")                                                \
            for (int kk = 0; kk < 2; ++kk)                                   \
                b[nj][kk] = LDB8(buf, br0 + nj * 16, quad + kk * 4);         \
        if (kt + 2 < NT12) stage_A(kt + 2);                                  \
        BAR(); LGKM0(); SCHED0();                                            \
        PRIO1(); MM(2); PRIO0();                                             \
        if (kt + 2 < NT12) {                                                 \
            if (wuni < 4) { VMC4(); } else { VMC0(); }                       \
        } else if (kt + 1 < NT12) { VMC0(); }                                \
        BAR();                                                               \
    }

__global__ __launch_bounds__(384, 3) void gemm_proj(
    const short* __restrict__ A, const short* __restrict__ Bt,
    const float* __restrict__ bias, float* __restrict__ Cout,
    int N, int nbx)
{
    __shared__ __align__(16) short As[2][128 * 64];   // 2 x 16 KB
    __shared__ __align__(16) short Bs[2][192 * 64];   // 2 x 24 KB  (total 80 KB)

    const int tid  = threadIdx.x;
    const int wave = tid >> 6;
    const int lane = tid & 63;
    const int ln15 = lane & 15;
    const int quad = lane >> 4;
    const int wm   = wave / 3;         // 0..1  (M, 64 rows each)
    const int wn   = wave % 3;         // 0..2  (N, 64 cols each)
    const int wuni = __builtin_amdgcn_readfirstlane(wave);  // uniform wave id

    // XCD-bijective swizzle: nwg = 64*nbx (divisible by 8); 8*nbx blocks/XCD
    const int orig = blockIdx.x;
    const int wg   = (orig & 7) * (8 * nbx) + (orig >> 3);
    const int bx   = wg % nbx;
    const int by   = wg / nbx;
    const int row0 = by * 128;
    const int col0 = bx * 192;

    const short* Ag = A  + (size_t)row0 * EMB;
    const short* Bg = Bt + (size_t)col0 * EMB;

    // ---- staging: 1-KB chunks, pre-swizzled global source (rule 21) ----
    auto stage_A = [&](int t) {
        if (wave >= 4) return;
        const int buf = t & 1;
        #pragma unroll
        for (int p = 0; p < 4; ++p) {
            const int id  = (wave * 4 + p) * 64 + lane;  // 0..1023
            const int row = id >> 3;                     // 0..127
            const int c   = (id & 7) ^ (row & 7);
            async_load16(Ag + (size_t)row * EMB + t * 64 + c * 8, &As[buf][id * 8]);
        }
    };
    auto stage_B = [&](int t) {
        const int buf = t & 1;
        #pragma unroll
        for (int p = 0; p < 4; ++p) {
            const int id  = (wave * 4 + p) * 64 + lane;  // 0..1535
            const int row = id >> 3;                     // 0..191
            const int c   = (id & 7) ^ (row & 7);
            async_load16(Bg + (size_t)row * EMB + t * 64 + c * 8, &Bs[buf][id * 8]);
        }
    };

    floatx4 acc[4][4];
    #pragma unroll
    for (int i = 0; i < 4; ++i)
        #pragma unroll
        for (int j = 0; j < 4; ++j) acc[i][j] = (floatx4){0.f, 0.f, 0.f, 0.f};

    short8 a[4][2];
    short8 b[4][2];

    // ---- prologue: A(0), B(0), A(1); keep A(1) in flight ----
    stage_A(0); stage_B(0); stage_A(1);
    if (wuni < 4) { VMC4(); } else { VMC0(); }
    BAR();

    const int ar0 = wm * 64 + ln15;
    const int br0 = wn * 64 + ln15;

    KLOOP2(MMA_T2)

    // ---- epilogue: trans acc (lane holds row r=..+ln15, cols c=..+quad*4+reg) ----
    const int wr = wm * 64, wc = wn * 64;
    float4 b4[4];
    #pragma unroll
    for (int j = 0; j < 4; ++j)
        b4[j] = *(const float4*)&bias[col0 + wc + j * 16 + quad * 4];
    #pragma unroll
    for (int i = 0; i < 4; ++i) {
        const int r = row0 + wr + i * 16 + ln15;
        #pragma unroll
        for (int j = 0; j < 4; ++j) {
            const int c = col0 + wc + j * 16 + quad * 4;
            float4 v;
            v.x = acc[i][j][0] + b4[j].x;
            v.y = acc[i][j][1] + b4[j].y;
            v.z = acc[i][j][2] + b4[j].z;
            v.w = acc[i][j][3] + b4[j].w;
            *(float4*)&Cout[(size_t)r * N + c] = v;
        }
    }
}

// ---------------------------------------------------------------------------
// MFMA flash attention — unchanged (passing) version: 64 Q rows/block,
// vt-based V^T staging, no max-tracking, deferred l, swizzled Ps round-trip.
// ---------------------------------------------------------------------------
#define LDK 72  // padded LDS row stride (shorts): 144 B

__global__ __launch_bounds__(256) void attn_mfma(
    const short* __restrict__ qkv, const short* __restrict__ vt,
    short* __restrict__ out)
{
    __shared__ __align__(16) short Ks[64 * LDK];     // K tile [kr][d]
    __shared__ __align__(16) short Vt[64 * LDK];     // V^T tile [d][kr]
    __shared__ __align__(16) short Ps[4 * 16 * LDK]; // per-wave P, swizzled

    const int tid  = threadIdx.x;
    const int wave = tid >> 6;
    const int lane = tid & 63;
    const int ln15 = lane & 15;
    const int quad = lane >> 4;

    const int qc = 15 - (int)(blockIdx.x / (BATCH * NH));   // heavy chunks first
    const int bh = blockIdx.x % (BATCH * NH);
    const int h  = bh % NH;
    const int b  = bh / NH;

    const int q0w = qc * 64 + wave * 16;

    const short* qkv_b = qkv + (size_t)b * SEQ * QKVW + h * HD;
    const short* Kg  = qkv_b + EMB;
    const short* Vtg = vt + ((size_t)b * EMB + h * HD) * SEQ;

    short8 qf[2];
    {
        const short* qrow = qkv_b + (size_t)(q0w + ln15) * QKVW;
        qf[0] = *(const short8*)(qrow + quad * 8);
        qf[1] = *(const short8*)(qrow + quad * 8 + 32);
    }

    floatx4 o[4];
    #pragma unroll
    for (int i = 0; i < 4; ++i) o[i] = (floatx4){0.f, 0.f, 0.f, 0.f};
    float lp[4] = {0.f, 0.f, 0.f, 0.f};   // per-lane l partials

    const int rr = tid >> 3;          // 0..31
    const int c8 = (tid & 7) * 8;     // 0..56

    for (int kt = 0; kt <= qc; ++kt) {
        // ---- stage K rows and V^T rows, b128 writes (conflict-free) ----
        #pragma unroll
        for (int p = 0; p < 2; ++p) {
            const int r2 = rr + p * 32;
            *(uint4*)&Ks[r2 * LDK + c8] =
                *(const uint4*)(Kg + (size_t)(kt * 64 + r2) * QKVW + c8);
            *(uint4*)&Vt[r2 * LDK + c8] =
                *(const uint4*)(Vtg + (size_t)r2 * SEQ + kt * 64 + c8);
        }
        __syncthreads();

        // ---- S = Q · K^T ----
        floatx4 s[4];
        #pragma unroll
        for (int i = 0; i < 4; ++i) s[i] = (floatx4){0.f, 0.f, 0.f, 0.f};
        #pragma unroll
        for (int st = 0; st < 2; ++st)
            #pragma unroll
            for (int sub = 0; sub < 4; ++sub) {
                const short8 kf = *(const short8*)&Ks[(ln15 + sub * 16) * LDK + quad * 8 + st * 32];
                s[sub] = __builtin_amdgcn_mfma_f32_16x16x32_bf16(qf[st], kf, s[sub], 0, 0, 0);
            }

        // ---- P = exp(S/8), causal mask on diagonal tile, accumulate l ----
        const bool diag = (kt == qc);
        #pragma unroll
        for (int sub = 0; sub < 4; ++sub)
            #pragma unroll
            for (int reg = 0; reg < 4; ++reg) {
                float pv = __expf(s[sub][reg] * 0.125f);
                if (diag && (ln15 + sub * 16 > wave * 16 + quad * 4 + reg)) pv = 0.f;
                s[sub][reg] = pv;
            }
        #pragma unroll
        for (int reg = 0; reg < 4; ++reg)
            lp[reg] += (s[0][reg] + s[1][reg]) + (s[2][reg] + s[3][reg]);

        // ---- P (C-layout) -> swizzled LDS -> A-layout fragments ----
        short* Pw = &Ps[wave * 16 * LDK];
        #pragma unroll
        for (int sub = 0; sub < 4; ++sub)
            #pragma unroll
            for (int reg = 0; reg < 4; ++reg) {
                const int qr   = quad * 4 + reg;
                const int kr8  = sub * 2 + (ln15 >> 3);
                const int slot = (kr8 + 5 * quad + reg) & 7;
                Pw[qr * LDK + slot * 8 + (ln15 & 7)] = f2bf(s[sub][reg]);
            }

        short8 pf[2];
        #pragma unroll
        for (int st = 0; st < 2; ++st) {
            const int slot = ((quad + 4 * st) + 5 * (ln15 >> 2) + (ln15 & 3)) & 7;
            pf[st] = *(const short8*)&Pw[ln15 * LDK + slot * 8];
        }

        // ---- O += P · V ----
        #pragma unroll
        for (int st = 0; st < 2; ++st)
            #pragma unroll
            for (int sub = 0; sub < 4; ++sub) {
                const short8 vf = *(const short8*)&Vt[(ln15 + sub * 16) * LDK + quad * 8 + st * 32];
                o[sub] = __builtin_amdgcn_mfma_f32_16x16x32_bf16(pf[st], vf, o[sub], 0, 0, 0);
            }

        __syncthreads();
    }

    // ---- epilogue: reduce l across the 16 lanes of each row, write O/l ----
    #pragma unroll
    for (int reg = 0; reg < 4; ++reg) {
        float t = lp[reg];
        #pragma unroll
        for (int off = 1; off <= 8; off <<= 1)
            t += __shfl_xor(t, off, 64);
        const float inv = 1.0f / t;
        const size_t row = (size_t)(b * SEQ + q0w + quad * 4 + reg) * EMB + h * HD;
        #pragma unroll
        for (int sub = 0; sub < 4; ++sub)
            out[row + ln15 + sub * 16] = f2bf(o[sub][reg] * inv);
    }
}

// ---------------------------------------------------------------------------
extern "C" void kernel_launch(void* const* d_in, const int* in_sizes, int n_in,
                              void* d_out, int out_size, void* d_ws, size_t ws_size,
                              hipStream_t stream)
{
    const float* x      = (const float*)d_in[0];   // [8,1024,768]
    const float* w_attn = (const float*)d_in[1];   // [768, 2304]
    const float* b_attn = (const float*)d_in[2];   // [2304]
    const float* w_proj = (const float*)d_in[3];   // [768, 768]
    const float* b_proj = (const float*)d_in[4];   // [768]
    float* out = (float*)d_out;                    // [8,1024,768] fp32

    const int M = BATCH * SEQ;       // 8192

    short* xb    = (short*)d_ws;                          // [8192, 768]
    short* waT   = xb    + (size_t)M * EMB;               // [2304, 768]
    short* wpT   = waT   + (size_t)QKVW * EMB;            // [768, 768]
    short* qkvb  = wpT   + (size_t)EMB * EMB;             // [8192, 2304] (V third unused)
    short* vtb   = qkvb  + (size_t)M * QKVW;              // [8, 768, 1024] V^T per head
    short* attnb = vtb   + (size_t)BATCH * EMB * SEQ;     // [8192, 768]

    dim3 blk(256);

    // 0) conversions
    cvt_bf16<<<dim3((M * EMB) / 8 / 256), blk, 0, stream>>>(x, xb, (M * EMB) / 8);
    transpose_to_bf16<<<dim3(QKVW / 32, EMB / 32), blk, 0, stream>>>(w_attn, waT, EMB, QKVW);
    transpose_to_bf16<<<dim3(EMB / 32, EMB / 32), blk, 0, stream>>>(w_proj, wpT, EMB, EMB);

    // 1) qkv = x @ w_attn + b_attn — round-2 256^2 deep-lead kernel (63.3 us)
    //    (Q/K -> qkvb bf16, V -> vtb transposed). 288 blocks x 512 threads.
    gemm_qkv_256<<<dim3((QKVW / 256) * (M / 256)), dim3(512), 0, stream>>>(
        xb, waT, b_attn, qkvb, vtb);

    // 2) causal MFMA flash attention -> attnb (bf16)
    attn_mfma<<<dim3(16 * BATCH * NH), blk, 0, stream>>>(qkvb, vtb, attnb);

    // 3) out = attn @ w_proj + b_proj — 128x192 pipelined kernel, grid 256,
    //    2 blocks/CU fully resident (round-3 measured win for this stage).
    gemm_proj<<<dim3((M / 128) * (EMB / 192)), dim3(384), 0, stream>>>(
        attnb, wpT, b_proj, out, EMB, EMB / 192);
}

// Round 6
// 200.661 us; speedup vs baseline: 1.0601x; 1.0601x over previous
//
#include <hip/hip_runtime.h>
#include <hip/hip_bf16.h>
#include <math.h>

// Problem constants (B=8, T=1024, EMB=768, H=12, D=64)
#define BATCH 8
#define SEQ   1024
#define EMB   768
#define NH    12
#define HD    64
#define QKVW  (3 * EMB)   // 2304
#define VOFF  (2 * EMB)   // 1536 — start of V columns in qkv

typedef short short8   __attribute__((ext_vector_type(8)));
typedef float floatx4  __attribute__((ext_vector_type(4)));

// fp32 -> bf16 (RNE) as raw short
__device__ __forceinline__ short f2bf(float f) {
    union { float f; unsigned u; } v; v.f = f;
    unsigned r = (v.u + 0x7fffu + ((v.u >> 16) & 1u)) >> 16;
    return (short)r;
}

// async 16B global -> LDS (wave-uniform base + lane*16 on the LDS side)
__device__ __forceinline__ void async_load16(const void* g, void* l) {
    __builtin_amdgcn_global_load_lds(
        (const __attribute__((address_space(1))) unsigned int*)g,
        (__attribute__((address_space(3))) unsigned int*)l, 16, 0, 0);
}

// ---------------------------------------------------------------------------
// fp32 -> bf16 elementwise (8 elems/thread)
// ---------------------------------------------------------------------------
__global__ __launch_bounds__(256) void cvt_bf16(
    const float* __restrict__ in, short* __restrict__ out, int n8)
{
    const int i = blockIdx.x * 256 + threadIdx.x;
    if (i >= n8) return;
    const float4 a = ((const float4*)in)[2 * i];
    const float4 b = ((const float4*)in)[2 * i + 1];
    short8 s;
    s[0] = f2bf(a.x); s[1] = f2bf(a.y); s[2] = f2bf(a.z); s[3] = f2bf(a.w);
    s[4] = f2bf(b.x); s[5] = f2bf(b.y); s[6] = f2bf(b.z); s[7] = f2bf(b.w);
    ((short8*)out)[i] = s;
}

// ---------------------------------------------------------------------------
// fp32 [R,C] -> bf16 [C,R] (transpose). R,C multiples of 32. Block 256 = 32x8.
// ---------------------------------------------------------------------------
__global__ __launch_bounds__(256) void transpose_to_bf16(
    const float* __restrict__ in, short* __restrict__ outT, int R, int C)
{
    __shared__ float t[32][33];
    const int c0 = blockIdx.x * 32, r0 = blockIdx.y * 32;
    const int lx = threadIdx.x & 31, ly = threadIdx.x >> 5;
    #pragma unroll
    for (int i = 0; i < 32; i += 8)
        t[ly + i][lx] = in[(size_t)(r0 + ly + i) * C + c0 + lx];
    __syncthreads();
    #pragma unroll
    for (int i = 0; i < 32; i += 8)
        outT[(size_t)(c0 + ly + i) * R + r0 + lx] = f2bf(t[lx][ly + i]);
}

// ---------------------------------------------------------------------------
// Shared schedule macros
// ---------------------------------------------------------------------------
#define NT12 (EMB / 64)   // 12 K-tiles

#define BAR()    do { asm volatile("" ::: "memory"); __builtin_amdgcn_s_barrier(); \
                      asm volatile("" ::: "memory"); } while (0)
#define LGKM0()  asm volatile("s_waitcnt lgkmcnt(0)" ::: "memory")
#define VMC0()   asm volatile("s_waitcnt vmcnt(0)" ::: "memory")
#define VMC4()   asm volatile("s_waitcnt vmcnt(4)" ::: "memory")
#define SCHED0() __builtin_amdgcn_sched_barrier(0)
#define PRIO1()  __builtin_amdgcn_s_setprio(1)
#define PRIO0()  __builtin_amdgcn_s_setprio(0)

// swizzled fragment read: logical k-chunk q of row r lives at physical chunk q^(r&7)
#define LDA(bf_, r_, q_) (*(const short8*)&As[bf_][(r_) * 64 + ((((q_)) ^ ((r_) & 7)) << 3)])
#define LDB(bf_, r_, q_) (*(const short8*)&Bs[bf_][(r_) * 64 + ((((q_)) ^ ((r_) & 7)) << 3)])

// 16 MFMAs: acc[IB..IB+3][JB..JB+1], kk-outer for 8-wide independence.
// _T: trans path (C^T accumulate, mfma(b,a)); _D: direct (mfma(a,b)).
#define MMA_T(IB, JB)                                                        \
    _Pragma("unroll")                                                        \
    for (int kk = 0; kk < 2; ++kk)                                           \
        _Pragma("unroll")                                                    \
        for (int mi = 0; mi < 4; ++mi)                                       \
            _Pragma("unroll")                                                \
            for (int nj = 0; nj < 2; ++nj)                                   \
                acc[(IB) + mi][(JB) + nj] =                                  \
                    __builtin_amdgcn_mfma_f32_16x16x32_bf16(                 \
                        b[(JB) + nj][kk], a[mi][kk],                         \
                        acc[(IB) + mi][(JB) + nj], 0, 0, 0);

#define MMA_D(IB, JB)                                                        \
    _Pragma("unroll")                                                        \
    for (int kk = 0; kk < 2; ++kk)                                           \
        _Pragma("unroll")                                                    \
        for (int mi = 0; mi < 4; ++mi)                                       \
            _Pragma("unroll")                                                \
            for (int nj = 0; nj < 2; ++nj)                                   \
                acc[(IB) + mi][(JB) + nj] =                                  \
                    __builtin_amdgcn_mfma_f32_16x16x32_bf16(                 \
                        a[mi][kk], b[(JB) + nj][kk],                         \
                        acc[(IB) + mi][(JB) + nj], 0, 0, 0);

// ---------------------------------------------------------------------------
// QKV GEMM: 128x128 tile / BK=64 / 4 waves (2M x 2N), per-wave 64x64
// (legacy acc[4][4] fragment+epilogue math). LDS = 64 KiB -> 2 blocks/CU;
// grid 1152 into 512 resident slots (dynamic dispatch smooths the tail that
// cost the 256^2 kernel a full 12.5%-utilization second round).
// Deep-lead 2-phase schedule (correct release points, unlike round 3):
//   P1: read a0-3+b01 of buf; stage B(kt+1) into buf^1 [B-reads of kt-1 from
//       buf^1 completed at (kt-1)P2-close barrier]
//   P2: read b23 of buf;      stage A(kt+2) into buf   [A-reads of kt from
//       buf completed at P1-close barrier]
//   one uniform vmcnt(4) per K-tile at P2-end: keeps only A(kt+2)'s 4 loads
//   in flight, guarantees tile kt+1 complete (A lead 2.5 phases, B 1.5).
// ---------------------------------------------------------------------------
#define KLOOPQ(MM)                                                           \
    for (int kt = 0; kt < NT12; ++kt) {                                      \
        const int buf = kt & 1;                                              \
        /* ---- P1: a0-3 (8 reads) + b01 (4 reads); stage B(kt+1) ---- */    \
        _Pragma("unroll")                                                    \
        for (int mi = 0; mi < 4; ++mi)                                       \
            _Pragma("unroll")                                                \
            for (int kk = 0; kk < 2; ++kk)                                   \
                a[mi][kk] = LDA(buf, ar0 + mi * 16, quad + kk * 4);          \
        _Pragma("unroll")                                                    \
        for (int nj = 0; nj < 2; ++nj)                                       \
            _Pragma("unroll")                                                \
            for (int kk = 0; kk < 2; ++kk)                                   \
                b[nj][kk] = LDB(buf, br0 + nj * 16, quad + kk * 4);          \
        if (kt + 1 < NT12) stage_B(kt + 1);                                  \
        BAR(); LGKM0(); SCHED0();                                            \
        PRIO1(); MM(0, 0); PRIO0();                                          \
        BAR();                                                               \
        /* ---- P2: b23 (4 reads); stage A(kt+2); counted wait ---- */       \
        _Pragma("unroll")                                                    \
        for (int nj = 2; nj < 4; ++nj)                                       \
            _Pragma("unroll")                                                \
            for (int kk = 0; kk < 2; ++kk)                                   \
                b[nj][kk] = LDB(buf, br0 + nj * 16, quad + kk * 4);          \
        if (kt + 2 < NT12) stage_A(kt + 2);                                  \
        BAR(); LGKM0(); SCHED0();                                            \
        PRIO1(); MM(0, 2); PRIO0();                                          \
        if (kt + 2 < NT12) { VMC4(); } else if (kt + 1 < NT12) { VMC0(); }   \
        BAR();                                                               \
    }

__global__ __launch_bounds__(256, 2) void gemm_qkv_128(
    const short* __restrict__ A, const short* __restrict__ Bt,
    const float* __restrict__ bias, short* __restrict__ qkvb,
    short* __restrict__ vt)
{
    __shared__ __align__(16) short As[2][128 * 64];   // 2 x 16 KB
    __shared__ __align__(16) short Bs[2][128 * 64];   // 2 x 16 KB (total 64 KB)

    const int tid  = threadIdx.x;
    const int wave = tid >> 6;         // 0..3
    const int lane = tid & 63;
    const int ln15 = lane & 15;
    const int quad = lane >> 4;
    const int wm   = wave >> 1;        // 0..1 (M, 64 rows each)
    const int wn   = wave & 1;         // 0..1 (N, 64 cols each)

    // XCD-bijective swizzle: 1152 blocks (1152 % 8 == 0), 144 per XCD.
    // Consecutive wg share the A row-panel -> L2-local per XCD.
    const int orig = blockIdx.x;
    const int wg   = (orig & 7) * 144 + (orig >> 3);
    const int bx   = wg % (QKVW / 128);   // 0..17
    const int by   = wg / (QKVW / 128);   // 0..63
    const int row0 = by * 128;
    const int col0 = bx * 128;
    const bool vpath = (col0 >= VOFF);    // col tiles 12..17 are V columns

    const short* Ag = A  + (size_t)row0 * EMB;
    const short* Bg = Bt + (size_t)col0 * EMB;

    // staging: 128 rows x 64 k = 16 KB = 1024 x 16B chunks; 4 loads/thread.
    // Pre-swizzled global source (rule 21): LDS linear, source chunk XORed.
    auto stage_A = [&](int t) {
        const int buf = t & 1;
        #pragma unroll
        for (int p = 0; p < 4; ++p) {
            const int id  = p * 256 + tid;        // 0..1023
            const int row = id >> 3;              // 0..127
            const int c   = (id & 7) ^ (row & 7);
            async_load16(Ag + (size_t)row * EMB + t * 64 + c * 8, &As[buf][id * 8]);
        }
    };
    auto stage_B = [&](int t) {
        const int buf = t & 1;
        #pragma unroll
        for (int p = 0; p < 4; ++p) {
            const int id  = p * 256 + tid;
            const int row = id >> 3;
            const int c   = (id & 7) ^ (row & 7);
            async_load16(Bg + (size_t)row * EMB + t * 64 + c * 8, &Bs[buf][id * 8]);
        }
    };

    floatx4 acc[4][4];
    #pragma unroll
    for (int i = 0; i < 4; ++i)
        #pragma unroll
        for (int j = 0; j < 4; ++j) acc[i][j] = (floatx4){0.f, 0.f, 0.f, 0.f};

    short8 a[4][2];
    short8 b[4][2];

    // ---- prologue: A(0), B(0), A(1); drain tile 0, keep A(1) in flight ----
    stage_A(0); stage_B(0); stage_A(1);
    VMC4();
    BAR();

    const int ar0 = wm * 64 + ln15;
    const int br0 = wn * 64 + ln15;

    if (vpath) { KLOOPQ(MMA_D) } else { KLOOPQ(MMA_T) }

    // ---- epilogue (legacy per-16x16 conventions, per-wave 64x64) ----
    const int wr = wm * 64, wc = wn * 64;
    if (!vpath) {
        // trans acc: lane holds row r = ...+ln15, cols c = ...+quad*4+reg
        #pragma unroll
        for (int j = 0; j < 4; ++j) {
            const float4 b4 = *(const float4*)&bias[col0 + wc + j * 16 + quad * 4];
            #pragma unroll
            for (int i = 0; i < 4; ++i) {
                const int r = row0 + wr + i * 16 + ln15;
                const int c = col0 + wc + j * 16 + quad * 4;
                union { short s[4]; unsigned long long u; } pk;
                pk.s[0] = f2bf(acc[i][j][0] + b4.x);
                pk.s[1] = f2bf(acc[i][j][1] + b4.y);
                pk.s[2] = f2bf(acc[i][j][2] + b4.z);
                pk.s[3] = f2bf(acc[i][j][3] + b4.w);
                *(unsigned long long*)&qkvb[(size_t)r * QKVW + c] = pk.u;
            }
        }
    } else {
        // direct acc: lane holds col c = ...+ln15, rows r = ...+quad*4+reg
        #pragma unroll
        for (int j = 0; j < 4; ++j) {
            const int c  = col0 + wc + j * 16 + ln15;
            const float bv = bias[c];
            const int c2 = c - VOFF;
            #pragma unroll
            for (int i = 0; i < 4; ++i) {
                const int r = row0 + wr + i * 16 + quad * 4;
                union { short s[4]; unsigned long long u; } pk;
                #pragma unroll
                for (int reg = 0; reg < 4; ++reg)
                    pk.s[reg] = f2bf(acc[i][j][reg] + bv);
                *(unsigned long long*)&vt[(size_t)(r >> 10) * (EMB * SEQ) +
                                          (size_t)c2 * SEQ + (r & 1023)] = pk.u;
            }
        }
    }
}

// ---------------------------------------------------------------------------
// Proj GEMM: 128x192 tile / BK=64 / 6 waves (2M x 3N), per-wave 64x64.
// LDS = 80 KiB -> 2 blocks/CU; grid 256 (fully resident, single round) —
// round-3 measured win for this stage. Unchanged.
// ---------------------------------------------------------------------------

#define LDA8(bf_, r_, q_) (*(const short8*)&As[bf_][(r_) * 64 + ((((q_)) ^ ((r_) & 7)) << 3)])
#define LDB8(bf_, r_, q_) (*(const short8*)&Bs[bf_][(r_) * 64 + ((((q_)) ^ ((r_) & 7)) << 3)])

#define MMA_T2(JB)                                                           \
    _Pragma("unroll")                                                        \
    for (int kk = 0; kk < 2; ++kk)                                           \
        _Pragma("unroll")                                                    \
        for (int mi = 0; mi < 4; ++mi)                                       \
            _Pragma("unroll")                                                \
            for (int nj = 0; nj < 2; ++nj)                                   \
                acc[mi][(JB) + nj] =                                         \
                    __builtin_amdgcn_mfma_f32_16x16x32_bf16(                 \
                        b[(JB) + nj][kk], a[mi][kk],                         \
                        acc[mi][(JB) + nj], 0, 0, 0);

#define KLOOP2(MM)                                                           \
    for (int kt = 0; kt < NT12; ++kt) {                                      \
        const int buf = kt & 1;                                              \
        /* ---- P1: all A frags (8) + b01 (4); stage B(kt+1) ---- */         \
        _Pragma("unroll")                                                    \
        for (int mi = 0; mi < 4; ++mi)                                       \
            _Pragma("unroll")                                                \
            for (int kk = 0; kk < 2; ++kk)                                   \
                a[mi][kk] = LDA8(buf, ar0 + mi * 16, quad + kk * 4);         \
        _Pragma("unroll")                                                    \
        for (int nj = 0; nj < 2; ++nj)                                       \
            _Pragma("unroll")                                                \
            for (int kk = 0; kk < 2; ++kk)                                   \
                b[nj][kk] = LDB8(buf, br0 + nj * 16, quad + kk * 4);         \
        if (kt + 1 < NT12) stage_B(kt + 1);                                  \
        BAR(); LGKM0(); SCHED0();                                            \
        PRIO1(); MM(0); PRIO0();                                             \
        BAR();                                                               \
        /* ---- P2: b23 (4); stage A(kt+2); counted wait ---- */             \
        _Pragma("unroll")                                                    \
        for (int nj = 2; nj < 4; ++nj)                                       \
            _Pragma("unroll")                                                \
            for (int kk = 0; kk < 2; ++kk)                                   \
                b[nj][kk] = LDB8(buf, br0 + nj * 16, quad + kk * 4);         \
        if (kt + 2 < NT12) stage_A(kt + 2);                                  \
        BAR(); LGKM0(); SCHED0();                                            \
        PRIO1(); MM(2); PRIO0();                                             \
        if (kt + 2 < NT12) {                                                 \
            if (wuni < 4) { VMC4(); } else { VMC0(); }                       \
        } else if (kt + 1 < NT12) { VMC0(); }                                \
        BAR();                                                               \
    }

__global__ __launch_bounds__(384, 3) void gemm_proj(
    const short* __restrict__ A, const short* __restrict__ Bt,
    const float* __restrict__ bias, float* __restrict__ Cout,
    int N, int nbx)
{
    __shared__ __align__(16) short As[2][128 * 64];   // 2 x 16 KB
    __shared__ __align__(16) short Bs[2][192 * 64];   // 2 x 24 KB  (total 80 KB)

    const int tid  = threadIdx.x;
    const int wave = tid >> 6;
    const int lane = tid & 63;
    const int ln15 = lane & 15;
    const int quad = lane >> 4;
    const int wm   = wave / 3;         // 0..1  (M, 64 rows each)
    const int wn   = wave % 3;         // 0..2  (N, 64 cols each)
    const int wuni = __builtin_amdgcn_readfirstlane(wave);  // uniform wave id

    // XCD-bijective swizzle: nwg = 64*nbx (divisible by 8); 8*nbx blocks/XCD
    const int orig = blockIdx.x;
    const int wg   = (orig & 7) * (8 * nbx) + (orig >> 3);
    const int bx   = wg % nbx;
    const int by   = wg / nbx;
    const int row0 = by * 128;
    const int col0 = bx * 192;

    const short* Ag = A  + (size_t)row0 * EMB;
    const short* Bg = Bt + (size_t)col0 * EMB;

    auto stage_A = [&](int t) {
        if (wave >= 4) return;
        const int buf = t & 1;
        #pragma unroll
        for (int p = 0; p < 4; ++p) {
            const int id  = (wave * 4 + p) * 64 + lane;  // 0..1023
            const int row = id >> 3;                     // 0..127
            const int c   = (id & 7) ^ (row & 7);
            async_load16(Ag + (size_t)row * EMB + t * 64 + c * 8, &As[buf][id * 8]);
        }
    };
    auto stage_B = [&](int t) {
        const int buf = t & 1;
        #pragma unroll
        for (int p = 0; p < 4; ++p) {
            const int id  = (wave * 4 + p) * 64 + lane;  // 0..1535
            const int row = id >> 3;                     // 0..191
            const int c   = (id & 7) ^ (row & 7);
            async_load16(Bg + (size_t)row * EMB + t * 64 + c * 8, &Bs[buf][id * 8]);
        }
    };

    floatx4 acc[4][4];
    #pragma unroll
    for (int i = 0; i < 4; ++i)
        #pragma unroll
        for (int j = 0; j < 4; ++j) acc[i][j] = (floatx4){0.f, 0.f, 0.f, 0.f};

    short8 a[4][2];
    short8 b[4][2];

    // ---- prologue: A(0), B(0), A(1); keep A(1) in flight ----
    stage_A(0); stage_B(0); stage_A(1);
    if (wuni < 4) { VMC4(); } else { VMC0(); }
    BAR();

    const int ar0 = wm * 64 + ln15;
    const int br0 = wn * 64 + ln15;

    KLOOP2(MMA_T2)

    // ---- epilogue: trans acc (lane holds row r=..+ln15, cols c=..+quad*4+reg) ----
    const int wr = wm * 64, wc = wn * 64;
    float4 b4[4];
    #pragma unroll
    for (int j = 0; j < 4; ++j)
        b4[j] = *(const float4*)&bias[col0 + wc + j * 16 + quad * 4];
    #pragma unroll
    for (int i = 0; i < 4; ++i) {
        const int r = row0 + wr + i * 16 + ln15;
        #pragma unroll
        for (int j = 0; j < 4; ++j) {
            const int c = col0 + wc + j * 16 + quad * 4;
            float4 v;
            v.x = acc[i][j][0] + b4[j].x;
            v.y = acc[i][j][1] + b4[j].y;
            v.z = acc[i][j][2] + b4[j].z;
            v.w = acc[i][j][3] + b4[j].w;
            *(float4*)&Cout[(size_t)r * N + c] = v;
        }
    }
}

// ---------------------------------------------------------------------------
// MFMA flash attention — unchanged (passing) version: 64 Q rows/block,
// vt-based V^T staging, no max-tracking, deferred l, swizzled Ps round-trip.
// ---------------------------------------------------------------------------
#define LDK 72  // padded LDS row stride (shorts): 144 B

__global__ __launch_bounds__(256) void attn_mfma(
    const short* __restrict__ qkv, const short* __restrict__ vt,
    short* __restrict__ out)
{
    __shared__ __align__(16) short Ks[64 * LDK];     // K tile [kr][d]
    __shared__ __align__(16) short Vt[64 * LDK];     // V^T tile [d][kr]
    __shared__ __align__(16) short Ps[4 * 16 * LDK]; // per-wave P, swizzled

    const int tid  = threadIdx.x;
    const int wave = tid >> 6;
    const int lane = tid & 63;
    const int ln15 = lane & 15;
    const int quad = lane >> 4;

    const int qc = 15 - (int)(blockIdx.x / (BATCH * NH));   // heavy chunks first
    const int bh = blockIdx.x % (BATCH * NH);
    const int h  = bh % NH;
    const int b  = bh / NH;

    const int q0w = qc * 64 + wave * 16;

    const short* qkv_b = qkv + (size_t)b * SEQ * QKVW + h * HD;
    const short* Kg  = qkv_b + EMB;
    const short* Vtg = vt + ((size_t)b * EMB + h * HD) * SEQ;

    short8 qf[2];
    {
        const short* qrow = qkv_b + (size_t)(q0w + ln15) * QKVW;
        qf[0] = *(const short8*)(qrow + quad * 8);
        qf[1] = *(const short8*)(qrow + quad * 8 + 32);
    }

    floatx4 o[4];
    #pragma unroll
    for (int i = 0; i < 4; ++i) o[i] = (floatx4){0.f, 0.f, 0.f, 0.f};
    float lp[4] = {0.f, 0.f, 0.f, 0.f};   // per-lane l partials

    const int rr = tid >> 3;          // 0..31
    const int c8 = (tid & 7) * 8;     // 0..56

    for (int kt = 0; kt <= qc; ++kt) {
        // ---- stage K rows and V^T rows, b128 writes (conflict-free) ----
        #pragma unroll
        for (int p = 0; p < 2; ++p) {
            const int r2 = rr + p * 32;
            *(uint4*)&Ks[r2 * LDK + c8] =
                *(const uint4*)(Kg + (size_t)(kt * 64 + r2) * QKVW + c8);
            *(uint4*)&Vt[r2 * LDK + c8] =
                *(const uint4*)(Vtg + (size_t)r2 * SEQ + kt * 64 + c8);
        }
        __syncthreads();

        // ---- S = Q · K^T ----
        floatx4 s[4];
        #pragma unroll
        for (int i = 0; i < 4; ++i) s[i] = (floatx4){0.f, 0.f, 0.f, 0.f};
        #pragma unroll
        for (int st = 0; st < 2; ++st)
            #pragma unroll
            for (int sub = 0; sub < 4; ++sub) {
                const short8 kf = *(const short8*)&Ks[(ln15 + sub * 16) * LDK + quad * 8 + st * 32];
                s[sub] = __builtin_amdgcn_mfma_f32_16x16x32_bf16(qf[st], kf, s[sub], 0, 0, 0);
            }

        // ---- P = exp(S/8), causal mask on diagonal tile, accumulate l ----
        const bool diag = (kt == qc);
        #pragma unroll
        for (int sub = 0; sub < 4; ++sub)
            #pragma unroll
            for (int reg = 0; reg < 4; ++reg) {
                float pv = __expf(s[sub][reg] * 0.125f);
                if (diag && (ln15 + sub * 16 > wave * 16 + quad * 4 + reg)) pv = 0.f;
                s[sub][reg] = pv;
            }
        #pragma unroll
        for (int reg = 0; reg < 4; ++reg)
            lp[reg] += (s[0][reg] + s[1][reg]) + (s[2][reg] + s[3][reg]);

        // ---- P (C-layout) -> swizzled LDS -> A-layout fragments ----
        short* Pw = &Ps[wave * 16 * LDK];
        #pragma unroll
        for (int sub = 0; sub < 4; ++sub)
            #pragma unroll
            for (int reg = 0; reg < 4; ++reg) {
                const int qr   = quad * 4 + reg;
                const int kr8  = sub * 2 + (ln15 >> 3);
                const int slot = (kr8 + 5 * quad + reg) & 7;
                Pw[qr * LDK + slot * 8 + (ln15 & 7)] = f2bf(s[sub][reg]);
            }

        short8 pf[2];
        #pragma unroll
        for (int st = 0; st < 2; ++st) {
            const int slot = ((quad + 4 * st) + 5 * (ln15 >> 2) + (ln15 & 3)) & 7;
            pf[st] = *(const short8*)&Pw[ln15 * LDK + slot * 8];
        }

        // ---- O += P · V ----
        #pragma unroll
        for (int st = 0; st < 2; ++st)
            #pragma unroll
            for (int sub = 0; sub < 4; ++sub) {
                const short8 vf = *(const short8*)&Vt[(ln15 + sub * 16) * LDK + quad * 8 + st * 32];
                o[sub] = __builtin_amdgcn_mfma_f32_16x16x32_bf16(pf[st], vf, o[sub], 0, 0, 0);
            }

        __syncthreads();
    }

    // ---- epilogue: reduce l across the 16 lanes of each row, write O/l ----
    #pragma unroll
    for (int reg = 0; reg < 4; ++reg) {
        float t = lp[reg];
        #pragma unroll
        for (int off = 1; off <= 8; off <<= 1)
            t += __shfl_xor(t, off, 64);
        const float inv = 1.0f / t;
        const size_t row = (size_t)(b * SEQ + q0w + quad * 4 + reg) * EMB + h * HD;
        #pragma unroll
        for (int sub = 0; sub < 4; ++sub)
            out[row + ln15 + sub * 16] = f2bf(o[sub][reg] * inv);
    }
}

// ---------------------------------------------------------------------------
extern "C" void kernel_launch(void* const* d_in, const int* in_sizes, int n_in,
                              void* d_out, int out_size, void* d_ws, size_t ws_size,
                              hipStream_t stream)
{
    const float* x      = (const float*)d_in[0];   // [8,1024,768]
    const float* w_attn = (const float*)d_in[1];   // [768, 2304]
    const float* b_attn = (const float*)d_in[2];   // [2304]
    const float* w_proj = (const float*)d_in[3];   // [768, 768]
    const float* b_proj = (const float*)d_in[4];   // [768]
    float* out = (float*)d_out;                    // [8,1024,768] fp32

    const int M = BATCH * SEQ;       // 8192

    short* xb    = (short*)d_ws;                          // [8192, 768]
    short* waT   = xb    + (size_t)M * EMB;               // [2304, 768]
    short* wpT   = waT   + (size_t)QKVW * EMB;            // [768, 768]
    short* qkvb  = wpT   + (size_t)EMB * EMB;             // [8192, 2304] (V third unused)
    short* vtb   = qkvb  + (size_t)M * QKVW;              // [8, 768, 1024] V^T per head
    short* attnb = vtb   + (size_t)BATCH * EMB * SEQ;     // [8192, 768]

    dim3 blk(256);

    // 0) conversions
    cvt_bf16<<<dim3((M * EMB) / 8 / 256), blk, 0, stream>>>(x, xb, (M * EMB) / 8);
    transpose_to_bf16<<<dim3(QKVW / 32, EMB / 32), blk, 0, stream>>>(w_attn, waT, EMB, QKVW);
    transpose_to_bf16<<<dim3(EMB / 32, EMB / 32), blk, 0, stream>>>(w_proj, wpT, EMB, EMB);

    // 1) qkv = x @ w_attn + b_attn — 128^2 deep-lead kernel, 1152 blocks,
    //    2 blocks/CU (Q/K -> qkvb bf16, V -> vtb transposed).
    gemm_qkv_128<<<dim3((M / 128) * (QKVW / 128)), blk, 0, stream>>>(
        xb, waT, b_attn, qkvb, vtb);

    // 2) causal MFMA flash attention -> attnb (bf16)
    attn_mfma<<<dim3(16 * BATCH * NH), blk, 0, stream>>>(qkvb, vtb, attnb);

    // 3) out = attn @ w_proj + b_proj — 128x192 pipelined kernel, grid 256,
    //    2 blocks/CU fully resident (round-3 measured win for this stage).
    gemm_proj<<<dim3((M / 128) * (EMB / 192)), dim3(384), 0, stream>>>(
        attnb, wpT, b_proj, out, EMB, EMB / 192);
}

// Round 7
// 193.854 us; speedup vs baseline: 1.0973x; 1.0351x over previous
//
#include <hip/hip_runtime.h>
#include <hip/hip_bf16.h>
#include <math.h>

// Problem constants (B=8, T=1024, EMB=768, H=12, D=64)
#define BATCH 8
#define SEQ   1024
#define EMB   768
#define NH    12
#define HD    64
#define QKVW  (3 * EMB)   // 2304
#define VOFF  (2 * EMB)   // 1536 — start of V columns in qkv

typedef short short8   __attribute__((ext_vector_type(8)));
typedef float floatx4  __attribute__((ext_vector_type(4)));

// fp32 -> bf16 (RNE) as raw short
__device__ __forceinline__ short f2bf(float f) {
    union { float f; unsigned u; } v; v.f = f;
    unsigned r = (v.u + 0x7fffu + ((v.u >> 16) & 1u)) >> 16;
    return (short)r;
}

// async 16B global -> LDS (wave-uniform base + lane*16 on the LDS side)
__device__ __forceinline__ void async_load16(const void* g, void* l) {
    __builtin_amdgcn_global_load_lds(
        (const __attribute__((address_space(1))) unsigned int*)g,
        (__attribute__((address_space(3))) unsigned int*)l, 16, 0, 0);
}

// ---------------------------------------------------------------------------
// fp32 -> bf16 elementwise (8 elems/thread)
// ---------------------------------------------------------------------------
__global__ __launch_bounds__(256) void cvt_bf16(
    const float* __restrict__ in, short* __restrict__ out, int n8)
{
    const int i = blockIdx.x * 256 + threadIdx.x;
    if (i >= n8) return;
    const float4 a = ((const float4*)in)[2 * i];
    const float4 b = ((const float4*)in)[2 * i + 1];
    short8 s;
    s[0] = f2bf(a.x); s[1] = f2bf(a.y); s[2] = f2bf(a.z); s[3] = f2bf(a.w);
    s[4] = f2bf(b.x); s[5] = f2bf(b.y); s[6] = f2bf(b.z); s[7] = f2bf(b.w);
    ((short8*)out)[i] = s;
}

// ---------------------------------------------------------------------------
// fp32 [R,C] -> bf16 [C,R] (transpose). R,C multiples of 32. Block 256 = 32x8.
// ---------------------------------------------------------------------------
__global__ __launch_bounds__(256) void transpose_to_bf16(
    const float* __restrict__ in, short* __restrict__ outT, int R, int C)
{
    __shared__ float t[32][33];
    const int c0 = blockIdx.x * 32, r0 = blockIdx.y * 32;
    const int lx = threadIdx.x & 31, ly = threadIdx.x >> 5;
    #pragma unroll
    for (int i = 0; i < 32; i += 8)
        t[ly + i][lx] = in[(size_t)(r0 + ly + i) * C + c0 + lx];
    __syncthreads();
    #pragma unroll
    for (int i = 0; i < 32; i += 8)
        outT[(size_t)(c0 + ly + i) * R + r0 + lx] = f2bf(t[lx][ly + i]);
}

// ---------------------------------------------------------------------------
// Shared schedule macros
// ---------------------------------------------------------------------------
#define NT12 (EMB / 64)   // 12 K-tiles

#define BAR()    do { asm volatile("" ::: "memory"); __builtin_amdgcn_s_barrier(); \
                      asm volatile("" ::: "memory"); } while (0)
#define LGKM0()  asm volatile("s_waitcnt lgkmcnt(0)" ::: "memory")
#define VMC0()   asm volatile("s_waitcnt vmcnt(0)" ::: "memory")
#define VMC4()   asm volatile("s_waitcnt vmcnt(4)" ::: "memory")
#define SCHED0() __builtin_amdgcn_sched_barrier(0)
#define PRIO1()  __builtin_amdgcn_s_setprio(1)
#define PRIO0()  __builtin_amdgcn_s_setprio(0)

// swizzled fragment read: logical k-chunk q of row r lives at physical chunk q^(r&7)
#define LDA(bf_, r_, q_) (*(const short8*)&As[bf_][(r_) * 64 + ((((q_)) ^ ((r_) & 7)) << 3)])
#define LDB(bf_, r_, q_) (*(const short8*)&Bs[bf_][(r_) * 64 + ((((q_)) ^ ((r_) & 7)) << 3)])

// 16 MFMAs: acc[IB..IB+3][JB..JB+1], kk-outer for 8-wide independence.
// _T: trans path (C^T accumulate, mfma(b,a)); _D: direct (mfma(a,b)).
#define MMA_T(IB, JB)                                                        \
    _Pragma("unroll")                                                        \
    for (int kk = 0; kk < 2; ++kk)                                           \
        _Pragma("unroll")                                                    \
        for (int mi = 0; mi < 4; ++mi)                                       \
            _Pragma("unroll")                                                \
            for (int nj = 0; nj < 2; ++nj)                                   \
                acc[(IB) + mi][(JB) + nj] =                                  \
                    __builtin_amdgcn_mfma_f32_16x16x32_bf16(                 \
                        b[(JB) + nj][kk], a[mi][kk],                         \
                        acc[(IB) + mi][(JB) + nj], 0, 0, 0);

#define MMA_D(IB, JB)                                                        \
    _Pragma("unroll")                                                        \
    for (int kk = 0; kk < 2; ++kk)                                           \
        _Pragma("unroll")                                                    \
        for (int mi = 0; mi < 4; ++mi)                                       \
            _Pragma("unroll")                                                \
            for (int nj = 0; nj < 2; ++nj)                                   \
                acc[(IB) + mi][(JB) + nj] =                                  \
                    __builtin_amdgcn_mfma_f32_16x16x32_bf16(                 \
                        a[mi][kk], b[(JB) + nj][kk],                         \
                        acc[(IB) + mi][(JB) + nj], 0, 0, 0);

// ---------------------------------------------------------------------------
// QKV GEMM: 128x128 tile / BK=64 / 4 waves (2M x 2N), per-wave 64x64.
// Unchanged from round 6 (65 us; equal-best measured for this stage).
// ---------------------------------------------------------------------------
#define KLOOPQ(MM)                                                           \
    for (int kt = 0; kt < NT12; ++kt) {                                      \
        const int buf = kt & 1;                                              \
        /* ---- P1: a0-3 (8 reads) + b01 (4 reads); stage B(kt+1) ---- */    \
        _Pragma("unroll")                                                    \
        for (int mi = 0; mi < 4; ++mi)                                       \
            _Pragma("unroll")                                                \
            for (int kk = 0; kk < 2; ++kk)                                   \
                a[mi][kk] = LDA(buf, ar0 + mi * 16, quad + kk * 4);          \
        _Pragma("unroll")                                                    \
        for (int nj = 0; nj < 2; ++nj)                                       \
            _Pragma("unroll")                                                \
            for (int kk = 0; kk < 2; ++kk)                                   \
                b[nj][kk] = LDB(buf, br0 + nj * 16, quad + kk * 4);          \
        if (kt + 1 < NT12) stage_B(kt + 1);                                  \
        BAR(); LGKM0(); SCHED0();                                            \
        PRIO1(); MM(0, 0); PRIO0();                                          \
        BAR();                                                               \
        /* ---- P2: b23 (4 reads); stage A(kt+2); counted wait ---- */       \
        _Pragma("unroll")                                                    \
        for (int nj = 2; nj < 4; ++nj)                                       \
            _Pragma("unroll")                                                \
            for (int kk = 0; kk < 2; ++kk)                                   \
                b[nj][kk] = LDB(buf, br0 + nj * 16, quad + kk * 4);          \
        if (kt + 2 < NT12) stage_A(kt + 2);                                  \
        BAR(); LGKM0(); SCHED0();                                            \
        PRIO1(); MM(0, 2); PRIO0();                                          \
        if (kt + 2 < NT12) { VMC4(); } else if (kt + 1 < NT12) { VMC0(); }   \
        BAR();                                                               \
    }

__global__ __launch_bounds__(256, 2) void gemm_qkv_128(
    const short* __restrict__ A, const short* __restrict__ Bt,
    const float* __restrict__ bias, short* __restrict__ qkvb,
    short* __restrict__ vt)
{
    __shared__ __align__(16) short As[2][128 * 64];   // 2 x 16 KB
    __shared__ __align__(16) short Bs[2][128 * 64];   // 2 x 16 KB (total 64 KB)

    const int tid  = threadIdx.x;
    const int wave = tid >> 6;         // 0..3
    const int lane = tid & 63;
    const int ln15 = lane & 15;
    const int quad = lane >> 4;
    const int wm   = wave >> 1;        // 0..1 (M, 64 rows each)
    const int wn   = wave & 1;         // 0..1 (N, 64 cols each)

    // XCD-bijective swizzle: 1152 blocks (1152 % 8 == 0), 144 per XCD.
    const int orig = blockIdx.x;
    const int wg   = (orig & 7) * 144 + (orig >> 3);
    const int bx   = wg % (QKVW / 128);   // 0..17
    const int by   = wg / (QKVW / 128);   // 0..63
    const int row0 = by * 128;
    const int col0 = bx * 128;
    const bool vpath = (col0 >= VOFF);    // col tiles 12..17 are V columns

    const short* Ag = A  + (size_t)row0 * EMB;
    const short* Bg = Bt + (size_t)col0 * EMB;

    // staging: 128 rows x 64 k = 16 KB = 1024 x 16B chunks; 4 loads/thread.
    // Pre-swizzled global source (rule 21): LDS linear, source chunk XORed.
    auto stage_A = [&](int t) {
        const int buf = t & 1;
        #pragma unroll
        for (int p = 0; p < 4; ++p) {
            const int id  = p * 256 + tid;        // 0..1023
            const int row = id >> 3;              // 0..127
            const int c   = (id & 7) ^ (row & 7);
            async_load16(Ag + (size_t)row * EMB + t * 64 + c * 8, &As[buf][id * 8]);
        }
    };
    auto stage_B = [&](int t) {
        const int buf = t & 1;
        #pragma unroll
        for (int p = 0; p < 4; ++p) {
            const int id  = p * 256 + tid;
            const int row = id >> 3;
            const int c   = (id & 7) ^ (row & 7);
            async_load16(Bg + (size_t)row * EMB + t * 64 + c * 8, &Bs[buf][id * 8]);
        }
    };

    floatx4 acc[4][4];
    #pragma unroll
    for (int i = 0; i < 4; ++i)
        #pragma unroll
        for (int j = 0; j < 4; ++j) acc[i][j] = (floatx4){0.f, 0.f, 0.f, 0.f};

    short8 a[4][2];
    short8 b[4][2];

    // ---- prologue: A(0), B(0), A(1); drain tile 0, keep A(1) in flight ----
    stage_A(0); stage_B(0); stage_A(1);
    VMC4();
    BAR();

    const int ar0 = wm * 64 + ln15;
    const int br0 = wn * 64 + ln15;

    if (vpath) { KLOOPQ(MMA_D) } else { KLOOPQ(MMA_T) }

    // ---- epilogue (legacy per-16x16 conventions, per-wave 64x64) ----
    const int wr = wm * 64, wc = wn * 64;
    if (!vpath) {
        // trans acc: lane holds row r = ...+ln15, cols c = ...+quad*4+reg
        #pragma unroll
        for (int j = 0; j < 4; ++j) {
            const float4 b4 = *(const float4*)&bias[col0 + wc + j * 16 + quad * 4];
            #pragma unroll
            for (int i = 0; i < 4; ++i) {
                const int r = row0 + wr + i * 16 + ln15;
                const int c = col0 + wc + j * 16 + quad * 4;
                union { short s[4]; unsigned long long u; } pk;
                pk.s[0] = f2bf(acc[i][j][0] + b4.x);
                pk.s[1] = f2bf(acc[i][j][1] + b4.y);
                pk.s[2] = f2bf(acc[i][j][2] + b4.z);
                pk.s[3] = f2bf(acc[i][j][3] + b4.w);
                *(unsigned long long*)&qkvb[(size_t)r * QKVW + c] = pk.u;
            }
        }
    } else {
        // direct acc: lane holds col c = ...+ln15, rows r = ...+quad*4+reg
        #pragma unroll
        for (int j = 0; j < 4; ++j) {
            const int c  = col0 + wc + j * 16 + ln15;
            const float bv = bias[c];
            const int c2 = c - VOFF;
            #pragma unroll
            for (int i = 0; i < 4; ++i) {
                const int r = row0 + wr + i * 16 + quad * 4;
                union { short s[4]; unsigned long long u; } pk;
                #pragma unroll
                for (int reg = 0; reg < 4; ++reg)
                    pk.s[reg] = f2bf(acc[i][j][reg] + bv);
                *(unsigned long long*)&vt[(size_t)(r >> 10) * (EMB * SEQ) +
                                          (size_t)c2 * SEQ + (r & 1023)] = pk.u;
            }
        }
    }
}

// ---------------------------------------------------------------------------
// Proj GEMM: 128x192 tile / BK=64 / 6 waves (2M x 3N), per-wave 64x64.
// Unchanged from round 6.
// ---------------------------------------------------------------------------

#define LDA8(bf_, r_, q_) (*(const short8*)&As[bf_][(r_) * 64 + ((((q_)) ^ ((r_) & 7)) << 3)])
#define LDB8(bf_, r_, q_) (*(const short8*)&Bs[bf_][(r_) * 64 + ((((q_)) ^ ((r_) & 7)) << 3)])

#define MMA_T2(JB)                                                           \
    _Pragma("unroll")                                                        \
    for (int kk = 0; kk < 2; ++kk)                                           \
        _Pragma("unroll")                                                    \
        for (int mi = 0; mi < 4; ++mi)                                       \
            _Pragma("unroll")                                                \
            for (int nj = 0; nj < 2; ++nj)                                   \
                acc[mi][(JB) + nj] =                                         \
                    __builtin_amdgcn_mfma_f32_16x16x32_bf16(                 \
                        b[(JB) + nj][kk], a[mi][kk],                         \
                        acc[mi][(JB) + nj], 0, 0, 0);

#define KLOOP2(MM)                                                           \
    for (int kt = 0; kt < NT12; ++kt) {                                      \
        const int buf = kt & 1;                                              \
        /* ---- P1: all A frags (8) + b01 (4); stage B(kt+1) ---- */         \
        _Pragma("unroll")                                                    \
        for (int mi = 0; mi < 4; ++mi)                                       \
            _Pragma("unroll")                                                \
            for (int kk = 0; kk < 2; ++kk)                                   \
                a[mi][kk] = LDA8(buf, ar0 + mi * 16, quad + kk * 4);         \
        _Pragma("unroll")                                                    \
        for (int nj = 0; nj < 2; ++nj)                                       \
            _Pragma("unroll")                                                \
            for (int kk = 0; kk < 2; ++kk)                                   \
                b[nj][kk] = LDB8(buf, br0 + nj * 16, quad + kk * 4);         \
        if (kt + 1 < NT12) stage_B(kt + 1);                                  \
        BAR(); LGKM0(); SCHED0();                                            \
        PRIO1(); MM(0); PRIO0();                                             \
        BAR();                                                               \
        /* ---- P2: b23 (4); stage A(kt+2); counted wait ---- */             \
        _Pragma("unroll")                                                    \
        for (int nj = 2; nj < 4; ++nj)                                       \
            _Pragma("unroll")                                                \
            for (int kk = 0; kk < 2; ++kk)                                   \
                b[nj][kk] = LDB8(buf, br0 + nj * 16, quad + kk * 4);         \
        if (kt + 2 < NT12) stage_A(kt + 2);                                  \
        BAR(); LGKM0(); SCHED0();                                            \
        PRIO1(); MM(2); PRIO0();                                             \
        if (kt + 2 < NT12) {                                                 \
            if (wuni < 4) { VMC4(); } else { VMC0(); }                       \
        } else if (kt + 1 < NT12) { VMC0(); }                                \
        BAR();                                                               \
    }

__global__ __launch_bounds__(384, 3) void gemm_proj(
    const short* __restrict__ A, const short* __restrict__ Bt,
    const float* __restrict__ bias, float* __restrict__ Cout,
    int N, int nbx)
{
    __shared__ __align__(16) short As[2][128 * 64];   // 2 x 16 KB
    __shared__ __align__(16) short Bs[2][192 * 64];   // 2 x 24 KB  (total 80 KB)

    const int tid  = threadIdx.x;
    const int wave = tid >> 6;
    const int lane = tid & 63;
    const int ln15 = lane & 15;
    const int quad = lane >> 4;
    const int wm   = wave / 3;         // 0..1  (M, 64 rows each)
    const int wn   = wave % 3;         // 0..2  (N, 64 cols each)
    const int wuni = __builtin_amdgcn_readfirstlane(wave);  // uniform wave id

    // XCD-bijective swizzle: nwg = 64*nbx (divisible by 8); 8*nbx blocks/XCD
    const int orig = blockIdx.x;
    const int wg   = (orig & 7) * (8 * nbx) + (orig >> 3);
    const int bx   = wg % nbx;
    const int by   = wg / nbx;
    const int row0 = by * 128;
    const int col0 = bx * 192;

    const short* Ag = A  + (size_t)row0 * EMB;
    const short* Bg = Bt + (size_t)col0 * EMB;

    auto stage_A = [&](int t) {
        if (wave >= 4) return;
        const int buf = t & 1;
        #pragma unroll
        for (int p = 0; p < 4; ++p) {
            const int id  = (wave * 4 + p) * 64 + lane;  // 0..1023
            const int row = id >> 3;                     // 0..127
            const int c   = (id & 7) ^ (row & 7);
            async_load16(Ag + (size_t)row * EMB + t * 64 + c * 8, &As[buf][id * 8]);
        }
    };
    auto stage_B = [&](int t) {
        const int buf = t & 1;
        #pragma unroll
        for (int p = 0; p < 4; ++p) {
            const int id  = (wave * 4 + p) * 64 + lane;  // 0..1535
            const int row = id >> 3;                     // 0..191
            const int c   = (id & 7) ^ (row & 7);
            async_load16(Bg + (size_t)row * EMB + t * 64 + c * 8, &Bs[buf][id * 8]);
        }
    };

    floatx4 acc[4][4];
    #pragma unroll
    for (int i = 0; i < 4; ++i)
        #pragma unroll
        for (int j = 0; j < 4; ++j) acc[i][j] = (floatx4){0.f, 0.f, 0.f, 0.f};

    short8 a[4][2];
    short8 b[4][2];

    // ---- prologue: A(0), B(0), A(1); keep A(1) in flight ----
    stage_A(0); stage_B(0); stage_A(1);
    if (wuni < 4) { VMC4(); } else { VMC0(); }
    BAR();

    const int ar0 = wm * 64 + ln15;
    const int br0 = wn * 64 + ln15;

    KLOOP2(MMA_T2)

    // ---- epilogue: trans acc (lane holds row r=..+ln15, cols c=..+quad*4+reg) ----
    const int wr = wm * 64, wc = wn * 64;
    float4 b4[4];
    #pragma unroll
    for (int j = 0; j < 4; ++j)
        b4[j] = *(const float4*)&bias[col0 + wc + j * 16 + quad * 4];
    #pragma unroll
    for (int i = 0; i < 4; ++i) {
        const int r = row0 + wr + i * 16 + ln15;
        #pragma unroll
        for (int j = 0; j < 4; ++j) {
            const int c = col0 + wc + j * 16 + quad * 4;
            float4 v;
            v.x = acc[i][j][0] + b4[j].x;
            v.y = acc[i][j][1] + b4[j].y;
            v.z = acc[i][j][2] + b4[j].z;
            v.w = acc[i][j][3] + b4[j].w;
            *(float4*)&Cout[(size_t)r * N + c] = v;
        }
    }
}

// ---------------------------------------------------------------------------
// MFMA flash attention — QBLK=128 (8 waves), single-buffered K/V with
// ASYNC LOAD-HOIST: next tile's global loads issue into registers right
// after the staging barrier and land during QK/softmax/PV (T14 mechanism).
// Halves block-iterations (13056 -> 6912), staging bytes, and barriers vs
// the 64-row version. Causal mask generalized to the global comparison
// (exactly equivalent on the old shape; fully-masked tiles add exact +0).
// Numerics and accumulation order identical -> absmax unchanged.
// ---------------------------------------------------------------------------
#define LDK 72  // padded LDS row stride (shorts): 144 B

__global__ __launch_bounds__(512) void attn_mfma(
    const short* __restrict__ qkv, const short* __restrict__ vt,
    short* __restrict__ out)
{
    __shared__ __align__(16) short Ks[64 * LDK];     // K tile [kr][d]     9 KB
    __shared__ __align__(16) short Vt[64 * LDK];     // V^T tile [d][kr]   9 KB
    __shared__ __align__(16) short Ps[8 * 16 * LDK]; // per-wave P        18 KB

    const int tid  = threadIdx.x;
    const int wave = tid >> 6;        // 0..7
    const int lane = tid & 63;
    const int ln15 = lane & 15;
    const int quad = lane >> 4;

    const int qc = 7 - (int)(blockIdx.x / (BATCH * NH));   // 0..7, heavy first
    const int bh = blockIdx.x % (BATCH * NH);
    const int h  = bh % NH;
    const int b  = bh / NH;

    const int q0w = qc * 128 + wave * 16;   // this wave's first Q row

    const short* qkv_b = qkv + (size_t)b * SEQ * QKVW + h * HD;
    const short* Kg  = qkv_b + EMB;
    const short* Vtg = vt + ((size_t)b * EMB + h * HD) * SEQ;

    short8 qf[2];
    {
        const short* qrow = qkv_b + (size_t)(q0w + ln15) * QKVW;
        qf[0] = *(const short8*)(qrow + quad * 8);
        qf[1] = *(const short8*)(qrow + quad * 8 + 32);
    }

    floatx4 o[4];
    #pragma unroll
    for (int i = 0; i < 4; ++i) o[i] = (floatx4){0.f, 0.f, 0.f, 0.f};
    float lp[4] = {0.f, 0.f, 0.f, 0.f};   // per-lane l partials

    const int rr = tid >> 3;          // 0..63  (tile row / d index)
    const int c8 = (tid & 7) * 8;     // 0..56

    const int nkt = 2 * qc + 2;       // KV tiles 0..nkt-1 cover cols 0..128qc+127

    // ---- prologue: load tile 0 into registers ----
    uint4 kreg = *(const uint4*)(Kg  + (size_t)rr * QKVW + c8);
    uint4 vreg = *(const uint4*)(Vtg + (size_t)rr * SEQ + c8);

    for (int kt = 0; kt < nkt; ++kt) {
        // ---- write staged regs to LDS (b128, conflict-free) ----
        *(uint4*)&Ks[rr * LDK + c8] = kreg;
        *(uint4*)&Vt[rr * LDK + c8] = vreg;
        __syncthreads();

        // ---- hoist next tile's loads; latency hides under compute ----
        if (kt + 1 < nkt) {
            kreg = *(const uint4*)(Kg  + (size_t)((kt + 1) * 64 + rr) * QKVW + c8);
            vreg = *(const uint4*)(Vtg + (size_t)rr * SEQ + (kt + 1) * 64 + c8);
        }

        // ---- S = Q · K^T ----
        floatx4 s[4];
        #pragma unroll
        for (int i = 0; i < 4; ++i) s[i] = (floatx4){0.f, 0.f, 0.f, 0.f};
        #pragma unroll
        for (int st = 0; st < 2; ++st)
            #pragma unroll
            for (int sub = 0; sub < 4; ++sub) {
                const short8 kf = *(const short8*)&Ks[(ln15 + sub * 16) * LDK + quad * 8 + st * 32];
                s[sub] = __builtin_amdgcn_mfma_f32_16x16x32_bf16(qf[st], kf, s[sub], 0, 0, 0);
            }

        // ---- P = exp(S/8), global causal mask, accumulate l ----
        #pragma unroll
        for (int sub = 0; sub < 4; ++sub)
            #pragma unroll
            for (int reg = 0; reg < 4; ++reg) {
                float pv = __expf(s[sub][reg] * 0.125f);
                if (kt * 64 + ln15 + sub * 16 > q0w + quad * 4 + reg) pv = 0.f;
                s[sub][reg] = pv;
            }
        #pragma unroll
        for (int reg = 0; reg < 4; ++reg)
            lp[reg] += (s[0][reg] + s[1][reg]) + (s[2][reg] + s[3][reg]);

        // ---- P (C-layout) -> swizzled LDS -> A-layout fragments ----
        short* Pw = &Ps[wave * 16 * LDK];
        #pragma unroll
        for (int sub = 0; sub < 4; ++sub)
            #pragma unroll
            for (int reg = 0; reg < 4; ++reg) {
                const int qr   = quad * 4 + reg;
                const int kr8  = sub * 2 + (ln15 >> 3);
                const int slot = (kr8 + 5 * quad + reg) & 7;
                Pw[qr * LDK + slot * 8 + (ln15 & 7)] = f2bf(s[sub][reg]);
            }

        short8 pf[2];
        #pragma unroll
        for (int st = 0; st < 2; ++st) {
            const int slot = ((quad + 4 * st) + 5 * (ln15 >> 2) + (ln15 & 3)) & 7;
            pf[st] = *(const short8*)&Pw[ln15 * LDK + slot * 8];
        }

        // ---- O += P · V ----
        #pragma unroll
        for (int st = 0; st < 2; ++st)
            #pragma unroll
            for (int sub = 0; sub < 4; ++sub) {
                const short8 vf = *(const short8*)&Vt[(ln15 + sub * 16) * LDK + quad * 8 + st * 32];
                o[sub] = __builtin_amdgcn_mfma_f32_16x16x32_bf16(pf[st], vf, o[sub], 0, 0, 0);
            }

        __syncthreads();
    }

    // ---- epilogue: reduce l across the 16 lanes of each row, write O/l ----
    #pragma unroll
    for (int reg = 0; reg < 4; ++reg) {
        float t = lp[reg];
        #pragma unroll
        for (int off = 1; off <= 8; off <<= 1)
            t += __shfl_xor(t, off, 64);
        const float inv = 1.0f / t;
        const size_t row = (size_t)(b * SEQ + q0w + quad * 4 + reg) * EMB + h * HD;
        #pragma unroll
        for (int sub = 0; sub < 4; ++sub)
            out[row + ln15 + sub * 16] = f2bf(o[sub][reg] * inv);
    }
}

// ---------------------------------------------------------------------------
extern "C" void kernel_launch(void* const* d_in, const int* in_sizes, int n_in,
                              void* d_out, int out_size, void* d_ws, size_t ws_size,
                              hipStream_t stream)
{
    const float* x      = (const float*)d_in[0];   // [8,1024,768]
    const float* w_attn = (const float*)d_in[1];   // [768, 2304]
    const float* b_attn = (const float*)d_in[2];   // [2304]
    const float* w_proj = (const float*)d_in[3];   // [768, 768]
    const float* b_proj = (const float*)d_in[4];   // [768]
    float* out = (float*)d_out;                    // [8,1024,768] fp32

    const int M = BATCH * SEQ;       // 8192

    short* xb    = (short*)d_ws;                          // [8192, 768]
    short* waT   = xb    + (size_t)M * EMB;               // [2304, 768]
    short* wpT   = waT   + (size_t)QKVW * EMB;            // [768, 768]
    short* qkvb  = wpT   + (size_t)EMB * EMB;             // [8192, 2304] (V third unused)
    short* vtb   = qkvb  + (size_t)M * QKVW;              // [8, 768, 1024] V^T per head
    short* attnb = vtb   + (size_t)BATCH * EMB * SEQ;     // [8192, 768]

    dim3 blk(256);

    // 0) conversions
    cvt_bf16<<<dim3((M * EMB) / 8 / 256), blk, 0, stream>>>(x, xb, (M * EMB) / 8);
    transpose_to_bf16<<<dim3(QKVW / 32, EMB / 32), blk, 0, stream>>>(w_attn, waT, EMB, QKVW);
    transpose_to_bf16<<<dim3(EMB / 32, EMB / 32), blk, 0, stream>>>(w_proj, wpT, EMB, EMB);

    // 1) qkv = x @ w_attn + b_attn — 128^2 deep-lead kernel, 1152 blocks,
    //    2 blocks/CU (Q/K -> qkvb bf16, V -> vtb transposed).
    gemm_qkv_128<<<dim3((M / 128) * (QKVW / 128)), blk, 0, stream>>>(
        xb, waT, b_attn, qkvb, vtb);

    // 2) causal MFMA flash attention — 128 Q rows/block, 8 waves,
    //    async load-hoist. 768 blocks x 512 threads, all resident.
    attn_mfma<<<dim3(8 * BATCH * NH), dim3(512), 0, stream>>>(qkvb, vtb, attnb);

    // 3) out = attn @ w_proj + b_proj — 128x192 pipelined kernel, grid 256,
    //    2 blocks/CU fully resident.
    gemm_proj<<<dim3((M / 128) * (EMB / 192)), dim3(384), 0, stream>>>(
        attnb, wpT, b_proj, out, EMB, EMB / 192);
}

// Round 8
// 188.977 us; speedup vs baseline: 1.1256x; 1.0258x over previous
//
#include <hip/hip_runtime.h>
#include <hip/hip_bf16.h>
#include <math.h>

// Problem constants (B=8, T=1024, EMB=768, H=12, D=64)
#define BATCH 8
#define SEQ   1024
#define EMB   768
#define NH    12
#define HD    64
#define QKVW  (3 * EMB)   // 2304
#define VOFF  (2 * EMB)   // 1536 — start of V columns in qkv

typedef short short8   __attribute__((ext_vector_type(8)));
typedef float floatx4  __attribute__((ext_vector_type(4)));

// fp32 -> bf16 (RNE) as raw short
__device__ __forceinline__ short f2bf(float f) {
    union { float f; unsigned u; } v; v.f = f;
    unsigned r = (v.u + 0x7fffu + ((v.u >> 16) & 1u)) >> 16;
    return (short)r;
}

// async 16B global -> LDS (wave-uniform base + lane*16 on the LDS side)
__device__ __forceinline__ void async_load16(const void* g, void* l) {
    __builtin_amdgcn_global_load_lds(
        (const __attribute__((address_space(1))) unsigned int*)g,
        (__attribute__((address_space(3))) unsigned int*)l, 16, 0, 0);
}

// ---------------------------------------------------------------------------
// Fused prep kernel (replaces cvt_bf16 + 2x transpose_to_bf16 launches):
//   blocks [0,3072):        x fp32 -> xb bf16 (8 elems/thread)
//   blocks [3072,4800):     w_attn [768,2304] -> waT bf16 [2304,768]
//   blocks [4800,5376):     w_proj [768,768]  -> wpT bf16 [768,768]
// Branch is block-uniform; bodies bit-identical to the verified kernels.
// ---------------------------------------------------------------------------
#define CVT_NB 3072            // (8192*768/8)/256
#define TA_NB  1728            // (2304/32)*(768/32)
#define PREP_NB (CVT_NB + TA_NB + 576)

__global__ __launch_bounds__(256) void prep(
    const float* __restrict__ x, const float* __restrict__ w_attn,
    const float* __restrict__ w_proj, short* __restrict__ xb,
    short* __restrict__ waT, short* __restrict__ wpT)
{
    __shared__ float t[32][33];
    const int bid = blockIdx.x;
    const int tid = threadIdx.x;

    if (bid < CVT_NB) {
        const int i = bid * 256 + tid;
        const float4 a = ((const float4*)x)[2 * i];
        const float4 b = ((const float4*)x)[2 * i + 1];
        short8 s;
        s[0] = f2bf(a.x); s[1] = f2bf(a.y); s[2] = f2bf(a.z); s[3] = f2bf(a.w);
        s[4] = f2bf(b.x); s[5] = f2bf(b.y); s[6] = f2bf(b.z); s[7] = f2bf(b.w);
        ((short8*)xb)[i] = s;
        return;
    }

    const float* in; short* outT; int ncb, idx;
    if (bid < CVT_NB + TA_NB) { idx = bid - CVT_NB; in = w_attn; outT = waT; ncb = QKVW / 32; }
    else                      { idx = bid - CVT_NB - TA_NB; in = w_proj; outT = wpT; ncb = EMB / 32; }
    const int C  = ncb * 32;              // row width of input
    const int c0 = (idx % ncb) * 32;
    const int r0 = (idx / ncb) * 32;
    const int lx = tid & 31, ly = tid >> 5;
    #pragma unroll
    for (int i = 0; i < 32; i += 8)
        t[ly + i][lx] = in[(size_t)(r0 + ly + i) * C + c0 + lx];
    __syncthreads();
    #pragma unroll
    for (int i = 0; i < 32; i += 8)
        outT[(size_t)(c0 + ly + i) * EMB + r0 + lx] = f2bf(t[lx][ly + i]);
}

// ---------------------------------------------------------------------------
// Shared schedule macros
// ---------------------------------------------------------------------------
#define NT12 (EMB / 64)   // 12 K-tiles

#define BAR()    do { asm volatile("" ::: "memory"); __builtin_amdgcn_s_barrier(); \
                      asm volatile("" ::: "memory"); } while (0)
#define LGKM0()  asm volatile("s_waitcnt lgkmcnt(0)" ::: "memory")
#define VMC0()   asm volatile("s_waitcnt vmcnt(0)" ::: "memory")
#define VMC4()   asm volatile("s_waitcnt vmcnt(4)" ::: "memory")
#define SCHED0() __builtin_amdgcn_sched_barrier(0)
#define PRIO1()  __builtin_amdgcn_s_setprio(1)
#define PRIO0()  __builtin_amdgcn_s_setprio(0)

// swizzled fragment read: logical k-chunk q of row r lives at physical chunk q^(r&7)
#define LDA(bf_, r_, q_) (*(const short8*)&As[bf_][(r_) * 64 + ((((q_)) ^ ((r_) & 7)) << 3)])
#define LDB(bf_, r_, q_) (*(const short8*)&Bs[bf_][(r_) * 64 + ((((q_)) ^ ((r_) & 7)) << 3)])

// 16 MFMAs: acc[IB..IB+3][JB..JB+1], kk-outer for 8-wide independence.
// _T: trans path (C^T accumulate, mfma(b,a)); _D: direct (mfma(a,b)).
#define MMA_T(IB, JB)                                                        \
    _Pragma("unroll")                                                        \
    for (int kk = 0; kk < 2; ++kk)                                           \
        _Pragma("unroll")                                                    \
        for (int mi = 0; mi < 4; ++mi)                                       \
            _Pragma("unroll")                                                \
            for (int nj = 0; nj < 2; ++nj)                                   \
                acc[(IB) + mi][(JB) + nj] =                                  \
                    __builtin_amdgcn_mfma_f32_16x16x32_bf16(                 \
                        b[(JB) + nj][kk], a[mi][kk],                         \
                        acc[(IB) + mi][(JB) + nj], 0, 0, 0);

#define MMA_D(IB, JB)                                                        \
    _Pragma("unroll")                                                        \
    for (int kk = 0; kk < 2; ++kk)                                           \
        _Pragma("unroll")                                                    \
        for (int mi = 0; mi < 4; ++mi)                                       \
            _Pragma("unroll")                                                \
            for (int nj = 0; nj < 2; ++nj)                                   \
                acc[(IB) + mi][(JB) + nj] =                                  \
                    __builtin_amdgcn_mfma_f32_16x16x32_bf16(                 \
                        a[mi][kk], b[(JB) + nj][kk],                         \
                        acc[(IB) + mi][(JB) + nj], 0, 0, 0);

// ---------------------------------------------------------------------------
// QKV GEMM: 128x128 tile / BK=64 / 4 waves (2M x 2N), per-wave 64x64.
// Unchanged (48-65 us measured band; equal-best structure for this stage).
// ---------------------------------------------------------------------------
#define KLOOPQ(MM)                                                           \
    for (int kt = 0; kt < NT12; ++kt) {                                      \
        const int buf = kt & 1;                                              \
        /* ---- P1: a0-3 (8 reads) + b01 (4 reads); stage B(kt+1) ---- */    \
        _Pragma("unroll")                                                    \
        for (int mi = 0; mi < 4; ++mi)                                       \
            _Pragma("unroll")                                                \
            for (int kk = 0; kk < 2; ++kk)                                   \
                a[mi][kk] = LDA(buf, ar0 + mi * 16, quad + kk * 4);          \
        _Pragma("unroll")                                                    \
        for (int nj = 0; nj < 2; ++nj)                                       \
            _Pragma("unroll")                                                \
            for (int kk = 0; kk < 2; ++kk)                                   \
                b[nj][kk] = LDB(buf, br0 + nj * 16, quad + kk * 4);          \
        if (kt + 1 < NT12) stage_B(kt + 1);                                  \
        BAR(); LGKM0(); SCHED0();                                            \
        PRIO1(); MM(0, 0); PRIO0();                                          \
        BAR();                                                               \
        /* ---- P2: b23 (4 reads); stage A(kt+2); counted wait ---- */       \
        _Pragma("unroll")                                                    \
        for (int nj = 2; nj < 4; ++nj)                                       \
            _Pragma("unroll")                                                \
            for (int kk = 0; kk < 2; ++kk)                                   \
                b[nj][kk] = LDB(buf, br0 + nj * 16, quad + kk * 4);          \
        if (kt + 2 < NT12) stage_A(kt + 2);                                  \
        BAR(); LGKM0(); SCHED0();                                            \
        PRIO1(); MM(0, 2); PRIO0();                                          \
        if (kt + 2 < NT12) { VMC4(); } else if (kt + 1 < NT12) { VMC0(); }   \
        BAR();                                                               \
    }

__global__ __launch_bounds__(256, 2) void gemm_qkv_128(
    const short* __restrict__ A, const short* __restrict__ Bt,
    const float* __restrict__ bias, short* __restrict__ qkvb,
    short* __restrict__ vt)
{
    __shared__ __align__(16) short As[2][128 * 64];   // 2 x 16 KB
    __shared__ __align__(16) short Bs[2][128 * 64];   // 2 x 16 KB (total 64 KB)

    const int tid  = threadIdx.x;
    const int wave = tid >> 6;         // 0..3
    const int lane = tid & 63;
    const int ln15 = lane & 15;
    const int quad = lane >> 4;
    const int wm   = wave >> 1;        // 0..1 (M, 64 rows each)
    const int wn   = wave & 1;         // 0..1 (N, 64 cols each)

    // XCD-bijective swizzle: 1152 blocks (1152 % 8 == 0), 144 per XCD.
    const int orig = blockIdx.x;
    const int wg   = (orig & 7) * 144 + (orig >> 3);
    const int bx   = wg % (QKVW / 128);   // 0..17
    const int by   = wg / (QKVW / 128);   // 0..63
    const int row0 = by * 128;
    const int col0 = bx * 128;
    const bool vpath = (col0 >= VOFF);    // col tiles 12..17 are V columns

    const short* Ag = A  + (size_t)row0 * EMB;
    const short* Bg = Bt + (size_t)col0 * EMB;

    // staging: 128 rows x 64 k = 16 KB = 1024 x 16B chunks; 4 loads/thread.
    // Pre-swizzled global source (rule 21): LDS linear, source chunk XORed.
    auto stage_A = [&](int t) {
        const int buf = t & 1;
        #pragma unroll
        for (int p = 0; p < 4; ++p) {
            const int id  = p * 256 + tid;        // 0..1023
            const int row = id >> 3;              // 0..127
            const int c   = (id & 7) ^ (row & 7);
            async_load16(Ag + (size_t)row * EMB + t * 64 + c * 8, &As[buf][id * 8]);
        }
    };
    auto stage_B = [&](int t) {
        const int buf = t & 1;
        #pragma unroll
        for (int p = 0; p < 4; ++p) {
            const int id  = p * 256 + tid;
            const int row = id >> 3;
            const int c   = (id & 7) ^ (row & 7);
            async_load16(Bg + (size_t)row * EMB + t * 64 + c * 8, &Bs[buf][id * 8]);
        }
    };

    floatx4 acc[4][4];
    #pragma unroll
    for (int i = 0; i < 4; ++i)
        #pragma unroll
        for (int j = 0; j < 4; ++j) acc[i][j] = (floatx4){0.f, 0.f, 0.f, 0.f};

    short8 a[4][2];
    short8 b[4][2];

    // ---- prologue: A(0), B(0), A(1); drain tile 0, keep A(1) in flight ----
    stage_A(0); stage_B(0); stage_A(1);
    VMC4();
    BAR();

    const int ar0 = wm * 64 + ln15;
    const int br0 = wn * 64 + ln15;

    if (vpath) { KLOOPQ(MMA_D) } else { KLOOPQ(MMA_T) }

    // ---- epilogue (legacy per-16x16 conventions, per-wave 64x64) ----
    const int wr = wm * 64, wc = wn * 64;
    if (!vpath) {
        // trans acc: lane holds row r = ...+ln15, cols c = ...+quad*4+reg
        #pragma unroll
        for (int j = 0; j < 4; ++j) {
            const float4 b4 = *(const float4*)&bias[col0 + wc + j * 16 + quad * 4];
            #pragma unroll
            for (int i = 0; i < 4; ++i) {
                const int r = row0 + wr + i * 16 + ln15;
                const int c = col0 + wc + j * 16 + quad * 4;
                union { short s[4]; unsigned long long u; } pk;
                pk.s[0] = f2bf(acc[i][j][0] + b4.x);
                pk.s[1] = f2bf(acc[i][j][1] + b4.y);
                pk.s[2] = f2bf(acc[i][j][2] + b4.z);
                pk.s[3] = f2bf(acc[i][j][3] + b4.w);
                *(unsigned long long*)&qkvb[(size_t)r * QKVW + c] = pk.u;
            }
        }
    } else {
        // direct acc: lane holds col c = ...+ln15, rows r = ...+quad*4+reg
        #pragma unroll
        for (int j = 0; j < 4; ++j) {
            const int c  = col0 + wc + j * 16 + ln15;
            const float bv = bias[c];
            const int c2 = c - VOFF;
            #pragma unroll
            for (int i = 0; i < 4; ++i) {
                const int r = row0 + wr + i * 16 + quad * 4;
                union { short s[4]; unsigned long long u; } pk;
                #pragma unroll
                for (int reg = 0; reg < 4; ++reg)
                    pk.s[reg] = f2bf(acc[i][j][reg] + bv);
                *(unsigned long long*)&vt[(size_t)(r >> 10) * (EMB * SEQ) +
                                          (size_t)c2 * SEQ + (r & 1023)] = pk.u;
            }
        }
    }
}

// ---------------------------------------------------------------------------
// Proj GEMM: 128x192 tile / BK=64 / 6 waves (2M x 3N), per-wave 64x64.
// Unchanged.
// ---------------------------------------------------------------------------

#define LDA8(bf_, r_, q_) (*(const short8*)&As[bf_][(r_) * 64 + ((((q_)) ^ ((r_) & 7)) << 3)])
#define LDB8(bf_, r_, q_) (*(const short8*)&Bs[bf_][(r_) * 64 + ((((q_)) ^ ((r_) & 7)) << 3)])

#define MMA_T2(JB)                                                           \
    _Pragma("unroll")                                                        \
    for (int kk = 0; kk < 2; ++kk)                                           \
        _Pragma("unroll")                                                    \
        for (int mi = 0; mi < 4; ++mi)                                       \
            _Pragma("unroll")                                                \
            for (int nj = 0; nj < 2; ++nj)                                   \
                acc[mi][(JB) + nj] =                                         \
                    __builtin_amdgcn_mfma_f32_16x16x32_bf16(                 \
                        b[(JB) + nj][kk], a[mi][kk],                         \
                        acc[mi][(JB) + nj], 0, 0, 0);

#define KLOOP2(MM)                                                           \
    for (int kt = 0; kt < NT12; ++kt) {                                      \
        const int buf = kt & 1;                                              \
        /* ---- P1: all A frags (8) + b01 (4); stage B(kt+1) ---- */         \
        _Pragma("unroll")                                                    \
        for (int mi = 0; mi < 4; ++mi)                                       \
            _Pragma("unroll")                                                \
            for (int kk = 0; kk < 2; ++kk)                                   \
                a[mi][kk] = LDA8(buf, ar0 + mi * 16, quad + kk * 4);         \
        _Pragma("unroll")                                                    \
        for (int nj = 0; nj < 2; ++nj)                                       \
            _Pragma("unroll")                                                \
            for (int kk = 0; kk < 2; ++kk)                                   \
                b[nj][kk] = LDB8(buf, br0 + nj * 16, quad + kk * 4);         \
        if (kt + 1 < NT12) stage_B(kt + 1);                                  \
        BAR(); LGKM0(); SCHED0();                                            \
        PRIO1(); MM(0); PRIO0();                                             \
        BAR();                                                               \
        /* ---- P2: b23 (4); stage A(kt+2); counted wait ---- */             \
        _Pragma("unroll")                                                    \
        for (int nj = 2; nj < 4; ++nj)                                       \
            _Pragma("unroll")                                                \
            for (int kk = 0; kk < 2; ++kk)                                   \
                b[nj][kk] = LDB8(buf, br0 + nj * 16, quad + kk * 4);         \
        if (kt + 2 < NT12) stage_A(kt + 2);                                  \
        BAR(); LGKM0(); SCHED0();                                            \
        PRIO1(); MM(2); PRIO0();                                             \
        if (kt + 2 < NT12) {                                                 \
            if (wuni < 4) { VMC4(); } else { VMC0(); }                       \
        } else if (kt + 1 < NT12) { VMC0(); }                                \
        BAR();                                                               \
    }

__global__ __launch_bounds__(384, 3) void gemm_proj(
    const short* __restrict__ A, const short* __restrict__ Bt,
    const float* __restrict__ bias, float* __restrict__ Cout,
    int N, int nbx)
{
    __shared__ __align__(16) short As[2][128 * 64];   // 2 x 16 KB
    __shared__ __align__(16) short Bs[2][192 * 64];   // 2 x 24 KB  (total 80 KB)

    const int tid  = threadIdx.x;
    const int wave = tid >> 6;
    const int lane = tid & 63;
    const int ln15 = lane & 15;
    const int quad = lane >> 4;
    const int wm   = wave / 3;         // 0..1  (M, 64 rows each)
    const int wn   = wave % 3;         // 0..2  (N, 64 cols each)
    const int wuni = __builtin_amdgcn_readfirstlane(wave);  // uniform wave id

    // XCD-bijective swizzle: nwg = 64*nbx (divisible by 8); 8*nbx blocks/XCD
    const int orig = blockIdx.x;
    const int wg   = (orig & 7) * (8 * nbx) + (orig >> 3);
    const int bx   = wg % nbx;
    const int by   = wg / nbx;
    const int row0 = by * 128;
    const int col0 = bx * 192;

    const short* Ag = A  + (size_t)row0 * EMB;
    const short* Bg = Bt + (size_t)col0 * EMB;

    auto stage_A = [&](int t) {
        if (wave >= 4) return;
        const int buf = t & 1;
        #pragma unroll
        for (int p = 0; p < 4; ++p) {
            const int id  = (wave * 4 + p) * 64 + lane;  // 0..1023
            const int row = id >> 3;                     // 0..127
            const int c   = (id & 7) ^ (row & 7);
            async_load16(Ag + (size_t)row * EMB + t * 64 + c * 8, &As[buf][id * 8]);
        }
    };
    auto stage_B = [&](int t) {
        const int buf = t & 1;
        #pragma unroll
        for (int p = 0; p < 4; ++p) {
            const int id  = (wave * 4 + p) * 64 + lane;  // 0..1535
            const int row = id >> 3;                     // 0..191
            const int c   = (id & 7) ^ (row & 7);
            async_load16(Bg + (size_t)row * EMB + t * 64 + c * 8, &Bs[buf][id * 8]);
        }
    };

    floatx4 acc[4][4];
    #pragma unroll
    for (int i = 0; i < 4; ++i)
        #pragma unroll
        for (int j = 0; j < 4; ++j) acc[i][j] = (floatx4){0.f, 0.f, 0.f, 0.f};

    short8 a[4][2];
    short8 b[4][2];

    // ---- prologue: A(0), B(0), A(1); keep A(1) in flight ----
    stage_A(0); stage_B(0); stage_A(1);
    if (wuni < 4) { VMC4(); } else { VMC0(); }
    BAR();

    const int ar0 = wm * 64 + ln15;
    const int br0 = wn * 64 + ln15;

    KLOOP2(MMA_T2)

    // ---- epilogue: trans acc (lane holds row r=..+ln15, cols c=..+quad*4+reg) ----
    const int wr = wm * 64, wc = wn * 64;
    float4 b4[4];
    #pragma unroll
    for (int j = 0; j < 4; ++j)
        b4[j] = *(const float4*)&bias[col0 + wc + j * 16 + quad * 4];
    #pragma unroll
    for (int i = 0; i < 4; ++i) {
        const int r = row0 + wr + i * 16 + ln15;
        #pragma unroll
        for (int j = 0; j < 4; ++j) {
            const int c = col0 + wc + j * 16 + quad * 4;
            float4 v;
            v.x = acc[i][j][0] + b4[j].x;
            v.y = acc[i][j][1] + b4[j].y;
            v.z = acc[i][j][2] + b4[j].z;
            v.w = acc[i][j][3] + b4[j].w;
            *(float4*)&Cout[(size_t)r * N + c] = v;
        }
    }
}

// ---------------------------------------------------------------------------
// MFMA flash attention — QBLK=128 (8 waves), single-buffered K/V with
// async load-hoist (round-7 verified). Unchanged.
// ---------------------------------------------------------------------------
#define LDK 72  // padded LDS row stride (shorts): 144 B

__global__ __launch_bounds__(512) void attn_mfma(
    const short* __restrict__ qkv, const short* __restrict__ vt,
    short* __restrict__ out)
{
    __shared__ __align__(16) short Ks[64 * LDK];     // K tile [kr][d]     9 KB
    __shared__ __align__(16) short Vt[64 * LDK];     // V^T tile [d][kr]   9 KB
    __shared__ __align__(16) short Ps[8 * 16 * LDK]; // per-wave P        18 KB

    const int tid  = threadIdx.x;
    const int wave = tid >> 6;        // 0..7
    const int lane = tid & 63;
    const int ln15 = lane & 15;
    const int quad = lane >> 4;

    const int qc = 7 - (int)(blockIdx.x / (BATCH * NH));   // 0..7, heavy first
    const int bh = blockIdx.x % (BATCH * NH);
    const int h  = bh % NH;
    const int b  = bh / NH;

    const int q0w = qc * 128 + wave * 16;   // this wave's first Q row

    const short* qkv_b = qkv + (size_t)b * SEQ * QKVW + h * HD;
    const short* Kg  = qkv_b + EMB;
    const short* Vtg = vt + ((size_t)b * EMB + h * HD) * SEQ;

    short8 qf[2];
    {
        const short* qrow = qkv_b + (size_t)(q0w + ln15) * QKVW;
        qf[0] = *(const short8*)(qrow + quad * 8);
        qf[1] = *(const short8*)(qrow + quad * 8 + 32);
    }

    floatx4 o[4];
    #pragma unroll
    for (int i = 0; i < 4; ++i) o[i] = (floatx4){0.f, 0.f, 0.f, 0.f};
    float lp[4] = {0.f, 0.f, 0.f, 0.f};   // per-lane l partials

    const int rr = tid >> 3;          // 0..63  (tile row / d index)
    const int c8 = (tid & 7) * 8;     // 0..56

    const int nkt = 2 * qc + 2;       // KV tiles 0..nkt-1 cover cols 0..128qc+127

    // ---- prologue: load tile 0 into registers ----
    uint4 kreg = *(const uint4*)(Kg  + (size_t)rr * QKVW + c8);
    uint4 vreg = *(const uint4*)(Vtg + (size_t)rr * SEQ + c8);

    for (int kt = 0; kt < nkt; ++kt) {
        // ---- write staged regs to LDS (b128, conflict-free) ----
        *(uint4*)&Ks[rr * LDK + c8] = kreg;
        *(uint4*)&Vt[rr * LDK + c8] = vreg;
        __syncthreads();

        // ---- hoist next tile's loads; latency hides under compute ----
        if (kt + 1 < nkt) {
            kreg = *(const uint4*)(Kg  + (size_t)((kt + 1) * 64 + rr) * QKVW + c8);
            vreg = *(const uint4*)(Vtg + (size_t)rr * SEQ + (kt + 1) * 64 + c8);
        }

        // ---- S = Q · K^T ----
        floatx4 s[4];
        #pragma unroll
        for (int i = 0; i < 4; ++i) s[i] = (floatx4){0.f, 0.f, 0.f, 0.f};
        #pragma unroll
        for (int st = 0; st < 2; ++st)
            #pragma unroll
            for (int sub = 0; sub < 4; ++sub) {
                const short8 kf = *(const short8*)&Ks[(ln15 + sub * 16) * LDK + quad * 8 + st * 32];
                s[sub] = __builtin_amdgcn_mfma_f32_16x16x32_bf16(qf[st], kf, s[sub], 0, 0, 0);
            }

        // ---- P = exp(S/8), global causal mask, accumulate l ----
        #pragma unroll
        for (int sub = 0; sub < 4; ++sub)
            #pragma unroll
            for (int reg = 0; reg < 4; ++reg) {
                float pv = __expf(s[sub][reg] * 0.125f);
                if (kt * 64 + ln15 + sub * 16 > q0w + quad * 4 + reg) pv = 0.f;
                s[sub][reg] = pv;
            }
        #pragma unroll
        for (int reg = 0; reg < 4; ++reg)
            lp[reg] += (s[0][reg] + s[1][reg]) + (s[2][reg] + s[3][reg]);

        // ---- P (C-layout) -> swizzled LDS -> A-layout fragments ----
        short* Pw = &Ps[wave * 16 * LDK];
        #pragma unroll
        for (int sub = 0; sub < 4; ++sub)
            #pragma unroll
            for (int reg = 0; reg < 4; ++reg) {
                const int qr   = quad * 4 + reg;
                const int kr8  = sub * 2 + (ln15 >> 3);
                const int slot = (kr8 + 5 * quad + reg) & 7;
                Pw[qr * LDK + slot * 8 + (ln15 & 7)] = f2bf(s[sub][reg]);
            }

        short8 pf[2];
        #pragma unroll
        for (int st = 0; st < 2; ++st) {
            const int slot = ((quad + 4 * st) + 5 * (ln15 >> 2) + (ln15 & 3)) & 7;
            pf[st] = *(const short8*)&Pw[ln15 * LDK + slot * 8];
        }

        // ---- O += P · V ----
        #pragma unroll
        for (int st = 0; st < 2; ++st)
            #pragma unroll
            for (int sub = 0; sub < 4; ++sub) {
                const short8 vf = *(const short8*)&Vt[(ln15 + sub * 16) * LDK + quad * 8 + st * 32];
                o[sub] = __builtin_amdgcn_mfma_f32_16x16x32_bf16(pf[st], vf, o[sub], 0, 0, 0);
            }

        __syncthreads();
    }

    // ---- epilogue: reduce l across the 16 lanes of each row, write O/l ----
    #pragma unroll
    for (int reg = 0; reg < 4; ++reg) {
        float t = lp[reg];
        #pragma unroll
        for (int off = 1; off <= 8; off <<= 1)
            t += __shfl_xor(t, off, 64);
        const float inv = 1.0f / t;
        const size_t row = (size_t)(b * SEQ + q0w + quad * 4 + reg) * EMB + h * HD;
        #pragma unroll
        for (int sub = 0; sub < 4; ++sub)
            out[row + ln15 + sub * 16] = f2bf(o[sub][reg] * inv);
    }
}

// ---------------------------------------------------------------------------
extern "C" void kernel_launch(void* const* d_in, const int* in_sizes, int n_in,
                              void* d_out, int out_size, void* d_ws, size_t ws_size,
                              hipStream_t stream)
{
    const float* x      = (const float*)d_in[0];   // [8,1024,768]
    const float* w_attn = (const float*)d_in[1];   // [768, 2304]
    const float* b_attn = (const float*)d_in[2];   // [2304]
    const float* w_proj = (const float*)d_in[3];   // [768, 768]
    const float* b_proj = (const float*)d_in[4];   // [768]
    float* out = (float*)d_out;                    // [8,1024,768] fp32

    const int M = BATCH * SEQ;       // 8192

    short* xb    = (short*)d_ws;                          // [8192, 768]
    short* waT   = xb    + (size_t)M * EMB;               // [2304, 768]
    short* wpT   = waT   + (size_t)QKVW * EMB;            // [768, 768]
    short* qkvb  = wpT   + (size_t)EMB * EMB;             // [8192, 2304] (V third unused)
    short* vtb   = qkvb  + (size_t)M * QKVW;              // [8, 768, 1024] V^T per head
    short* attnb = vtb   + (size_t)BATCH * EMB * SEQ;     // [8192, 768]

    // 0) fused conversions (1 launch instead of 3)
    prep<<<dim3(PREP_NB), dim3(256), 0, stream>>>(x, w_attn, w_proj, xb, waT, wpT);

    // 1) qkv = x @ w_attn + b_attn — 128^2 deep-lead kernel, 1152 blocks,
    //    2 blocks/CU (Q/K -> qkvb bf16, V -> vtb transposed).
    gemm_qkv_128<<<dim3((M / 128) * (QKVW / 128)), dim3(256), 0, stream>>>(
        xb, waT, b_attn, qkvb, vtb);

    // 2) causal MFMA flash attention — 128 Q rows/block, 8 waves,
    //    async load-hoist. 768 blocks x 512 threads, all resident.
    attn_mfma<<<dim3(8 * BATCH * NH), dim3(512), 0, stream>>>(qkvb, vtb, attnb);

    // 3) out = attn @ w_proj + b_proj — 128x192 pipelined kernel, grid 256,
    //    2 blocks/CU fully resident.
    gemm_proj<<<dim3((M / 128) * (EMB / 192)), dim3(384), 0, stream>>>(
        attnb, wpT, b_proj, out, EMB, EMB / 192);
}

// Round 9
// 188.612 us; speedup vs baseline: 1.1278x; 1.0019x over previous
//
#include <hip/hip_runtime.h>
#include <hip/hip_bf16.h>
#include <math.h>

// Problem constants (B=8, T=1024, EMB=768, H=12, D=64)
#define BATCH 8
#define SEQ   1024
#define EMB   768
#define NH    12
#define HD    64
#define QKVW  (3 * EMB)   // 2304
#define VOFF  (2 * EMB)   // 1536 — start of V columns in qkv

typedef short short8   __attribute__((ext_vector_type(8)));
typedef float floatx4  __attribute__((ext_vector_type(4)));

// fp32 -> bf16 (RNE) as raw short
__device__ __forceinline__ short f2bf(float f) {
    union { float f; unsigned u; } v; v.f = f;
    unsigned r = (v.u + 0x7fffu + ((v.u >> 16) & 1u)) >> 16;
    return (short)r;
}

// async 16B global -> LDS (wave-uniform base + lane*16 on the LDS side)
__device__ __forceinline__ void async_load16(const void* g, void* l) {
    __builtin_amdgcn_global_load_lds(
        (const __attribute__((address_space(1))) unsigned int*)g,
        (__attribute__((address_space(3))) unsigned int*)l, 16, 0, 0);
}

// ---------------------------------------------------------------------------
// Fused prep kernel (replaces cvt_bf16 + 2x transpose_to_bf16 launches):
//   blocks [0,3072):        x fp32 -> xb bf16 (8 elems/thread)
//   blocks [3072,4800):     w_attn [768,2304] -> waT bf16 [2304,768]
//   blocks [4800,5376):     w_proj [768,768]  -> wpT bf16 [768,768]
// Branch is block-uniform; bodies bit-identical to the verified kernels.
// ---------------------------------------------------------------------------
#define CVT_NB 3072            // (8192*768/8)/256
#define TA_NB  1728            // (2304/32)*(768/32)
#define PREP_NB (CVT_NB + TA_NB + 576)

__global__ __launch_bounds__(256) void prep(
    const float* __restrict__ x, const float* __restrict__ w_attn,
    const float* __restrict__ w_proj, short* __restrict__ xb,
    short* __restrict__ waT, short* __restrict__ wpT)
{
    __shared__ float t[32][33];
    const int bid = blockIdx.x;
    const int tid = threadIdx.x;

    if (bid < CVT_NB) {
        const int i = bid * 256 + tid;
        const float4 a = ((const float4*)x)[2 * i];
        const float4 b = ((const float4*)x)[2 * i + 1];
        short8 s;
        s[0] = f2bf(a.x); s[1] = f2bf(a.y); s[2] = f2bf(a.z); s[3] = f2bf(a.w);
        s[4] = f2bf(b.x); s[5] = f2bf(b.y); s[6] = f2bf(b.z); s[7] = f2bf(b.w);
        ((short8*)xb)[i] = s;
        return;
    }

    const float* in; short* outT; int ncb, idx;
    if (bid < CVT_NB + TA_NB) { idx = bid - CVT_NB; in = w_attn; outT = waT; ncb = QKVW / 32; }
    else                      { idx = bid - CVT_NB - TA_NB; in = w_proj; outT = wpT; ncb = EMB / 32; }
    const int C  = ncb * 32;              // row width of input
    const int c0 = (idx % ncb) * 32;
    const int r0 = (idx / ncb) * 32;
    const int lx = tid & 31, ly = tid >> 5;
    #pragma unroll
    for (int i = 0; i < 32; i += 8)
        t[ly + i][lx] = in[(size_t)(r0 + ly + i) * C + c0 + lx];
    __syncthreads();
    #pragma unroll
    for (int i = 0; i < 32; i += 8)
        outT[(size_t)(c0 + ly + i) * EMB + r0 + lx] = f2bf(t[lx][ly + i]);
}

// ---------------------------------------------------------------------------
// Shared schedule macros
// ---------------------------------------------------------------------------
#define NT12 (EMB / 64)   // 12 K-tiles

#define BAR()    do { asm volatile("" ::: "memory"); __builtin_amdgcn_s_barrier(); \
                      asm volatile("" ::: "memory"); } while (0)
#define LGKM0()  asm volatile("s_waitcnt lgkmcnt(0)" ::: "memory")
#define VMC0()   asm volatile("s_waitcnt vmcnt(0)" ::: "memory")
#define VMC4()   asm volatile("s_waitcnt vmcnt(4)" ::: "memory")
#define SCHED0() __builtin_amdgcn_sched_barrier(0)
#define PRIO1()  __builtin_amdgcn_s_setprio(1)
#define PRIO0()  __builtin_amdgcn_s_setprio(0)

// swizzled fragment read: logical k-chunk q of row r lives at physical chunk q^(r&7)
#define LDA(bf_, r_, q_) (*(const short8*)&As[bf_][(r_) * 64 + ((((q_)) ^ ((r_) & 7)) << 3)])
#define LDB(bf_, r_, q_) (*(const short8*)&Bs[bf_][(r_) * 64 + ((((q_)) ^ ((r_) & 7)) << 3)])

// 16 MFMAs: acc[IB..IB+3][JB..JB+1], kk-outer for 8-wide independence.
// _T: trans path (C^T accumulate, mfma(b,a)); _D: direct (mfma(a,b)).
#define MMA_T(IB, JB)                                                        \
    _Pragma("unroll")                                                        \
    for (int kk = 0; kk < 2; ++kk)                                           \
        _Pragma("unroll")                                                    \
        for (int mi = 0; mi < 4; ++mi)                                       \
            _Pragma("unroll")                                                \
            for (int nj = 0; nj < 2; ++nj)                                   \
                acc[(IB) + mi][(JB) + nj] =                                  \
                    __builtin_amdgcn_mfma_f32_16x16x32_bf16(                 \
                        b[(JB) + nj][kk], a[mi][kk],                         \
                        acc[(IB) + mi][(JB) + nj], 0, 0, 0);

#define MMA_D(IB, JB)                                                        \
    _Pragma("unroll")                                                        \
    for (int kk = 0; kk < 2; ++kk)                                           \
        _Pragma("unroll")                                                    \
        for (int mi = 0; mi < 4; ++mi)                                       \
            _Pragma("unroll")                                                \
            for (int nj = 0; nj < 2; ++nj)                                   \
                acc[(IB) + mi][(JB) + nj] =                                  \
                    __builtin_amdgcn_mfma_f32_16x16x32_bf16(                 \
                        a[mi][kk], b[(JB) + nj][kk],                         \
                        acc[(IB) + mi][(JB) + nj], 0, 0, 0);

// ---------------------------------------------------------------------------
// QKV GEMM: 128x128 tile / BK=64 / 4 waves (2M x 2N), per-wave 64x64.
// Unchanged (46 us measured, stable across rounds 7-8).
// ---------------------------------------------------------------------------
#define KLOOPQ(MM)                                                           \
    for (int kt = 0; kt < NT12; ++kt) {                                      \
        const int buf = kt & 1;                                              \
        /* ---- P1: a0-3 (8 reads) + b01 (4 reads); stage B(kt+1) ---- */    \
        _Pragma("unroll")                                                    \
        for (int mi = 0; mi < 4; ++mi)                                       \
            _Pragma("unroll")                                                \
            for (int kk = 0; kk < 2; ++kk)                                   \
                a[mi][kk] = LDA(buf, ar0 + mi * 16, quad + kk * 4);          \
        _Pragma("unroll")                                                    \
        for (int nj = 0; nj < 2; ++nj)                                       \
            _Pragma("unroll")                                                \
            for (int kk = 0; kk < 2; ++kk)                                   \
                b[nj][kk] = LDB(buf, br0 + nj * 16, quad + kk * 4);          \
        if (kt + 1 < NT12) stage_B(kt + 1);                                  \
        BAR(); LGKM0(); SCHED0();                                            \
        PRIO1(); MM(0, 0); PRIO0();                                          \
        BAR();                                                               \
        /* ---- P2: b23 (4 reads); stage A(kt+2); counted wait ---- */       \
        _Pragma("unroll")                                                    \
        for (int nj = 2; nj < 4; ++nj)                                       \
            _Pragma("unroll")                                                \
            for (int kk = 0; kk < 2; ++kk)                                   \
                b[nj][kk] = LDB(buf, br0 + nj * 16, quad + kk * 4);          \
        if (kt + 2 < NT12) stage_A(kt + 2);                                  \
        BAR(); LGKM0(); SCHED0();                                            \
        PRIO1(); MM(0, 2); PRIO0();                                          \
        if (kt + 2 < NT12) { VMC4(); } else if (kt + 1 < NT12) { VMC0(); }   \
        BAR();                                                               \
    }

__global__ __launch_bounds__(256, 2) void gemm_qkv_128(
    const short* __restrict__ A, const short* __restrict__ Bt,
    const float* __restrict__ bias, short* __restrict__ qkvb,
    short* __restrict__ vt)
{
    __shared__ __align__(16) short As[2][128 * 64];   // 2 x 16 KB
    __shared__ __align__(16) short Bs[2][128 * 64];   // 2 x 16 KB (total 64 KB)

    const int tid  = threadIdx.x;
    const int wave = tid >> 6;         // 0..3
    const int lane = tid & 63;
    const int ln15 = lane & 15;
    const int quad = lane >> 4;
    const int wm   = wave >> 1;        // 0..1 (M, 64 rows each)
    const int wn   = wave & 1;         // 0..1 (N, 64 cols each)

    // XCD-bijective swizzle: 1152 blocks (1152 % 8 == 0), 144 per XCD.
    const int orig = blockIdx.x;
    const int wg   = (orig & 7) * 144 + (orig >> 3);
    const int bx   = wg % (QKVW / 128);   // 0..17
    const int by   = wg / (QKVW / 128);   // 0..63
    const int row0 = by * 128;
    const int col0 = bx * 128;
    const bool vpath = (col0 >= VOFF);    // col tiles 12..17 are V columns

    const short* Ag = A  + (size_t)row0 * EMB;
    const short* Bg = Bt + (size_t)col0 * EMB;

    // staging: 128 rows x 64 k = 16 KB = 1024 x 16B chunks; 4 loads/thread.
    // Pre-swizzled global source (rule 21): LDS linear, source chunk XORed.
    auto stage_A = [&](int t) {
        const int buf = t & 1;
        #pragma unroll
        for (int p = 0; p < 4; ++p) {
            const int id  = p * 256 + tid;        // 0..1023
            const int row = id >> 3;              // 0..127
            const int c   = (id & 7) ^ (row & 7);
            async_load16(Ag + (size_t)row * EMB + t * 64 + c * 8, &As[buf][id * 8]);
        }
    };
    auto stage_B = [&](int t) {
        const int buf = t & 1;
        #pragma unroll
        for (int p = 0; p < 4; ++p) {
            const int id  = p * 256 + tid;
            const int row = id >> 3;
            const int c   = (id & 7) ^ (row & 7);
            async_load16(Bg + (size_t)row * EMB + t * 64 + c * 8, &Bs[buf][id * 8]);
        }
    };

    floatx4 acc[4][4];
    #pragma unroll
    for (int i = 0; i < 4; ++i)
        #pragma unroll
        for (int j = 0; j < 4; ++j) acc[i][j] = (floatx4){0.f, 0.f, 0.f, 0.f};

    short8 a[4][2];
    short8 b[4][2];

    // ---- prologue: A(0), B(0), A(1); drain tile 0, keep A(1) in flight ----
    stage_A(0); stage_B(0); stage_A(1);
    VMC4();
    BAR();

    const int ar0 = wm * 64 + ln15;
    const int br0 = wn * 64 + ln15;

    if (vpath) { KLOOPQ(MMA_D) } else { KLOOPQ(MMA_T) }

    // ---- epilogue (legacy per-16x16 conventions, per-wave 64x64) ----
    const int wr = wm * 64, wc = wn * 64;
    if (!vpath) {
        // trans acc: lane holds row r = ...+ln15, cols c = ...+quad*4+reg
        #pragma unroll
        for (int j = 0; j < 4; ++j) {
            const float4 b4 = *(const float4*)&bias[col0 + wc + j * 16 + quad * 4];
            #pragma unroll
            for (int i = 0; i < 4; ++i) {
                const int r = row0 + wr + i * 16 + ln15;
                const int c = col0 + wc + j * 16 + quad * 4;
                union { short s[4]; unsigned long long u; } pk;
                pk.s[0] = f2bf(acc[i][j][0] + b4.x);
                pk.s[1] = f2bf(acc[i][j][1] + b4.y);
                pk.s[2] = f2bf(acc[i][j][2] + b4.z);
                pk.s[3] = f2bf(acc[i][j][3] + b4.w);
                *(unsigned long long*)&qkvb[(size_t)r * QKVW + c] = pk.u;
            }
        }
    } else {
        // direct acc: lane holds col c = ...+ln15, rows r = ...+quad*4+reg
        #pragma unroll
        for (int j = 0; j < 4; ++j) {
            const int c  = col0 + wc + j * 16 + ln15;
            const float bv = bias[c];
            const int c2 = c - VOFF;
            #pragma unroll
            for (int i = 0; i < 4; ++i) {
                const int r = row0 + wr + i * 16 + quad * 4;
                union { short s[4]; unsigned long long u; } pk;
                #pragma unroll
                for (int reg = 0; reg < 4; ++reg)
                    pk.s[reg] = f2bf(acc[i][j][reg] + bv);
                *(unsigned long long*)&vt[(size_t)(r >> 10) * (EMB * SEQ) +
                                          (size_t)c2 * SEQ + (r & 1023)] = pk.u;
            }
        }
    }
}

// ---------------------------------------------------------------------------
// Proj GEMM: 128x192 tile / BK=64 / 6 waves (2M x 3N), per-wave 64x64.
// Unchanged.
// ---------------------------------------------------------------------------

#define LDA8(bf_, r_, q_) (*(const short8*)&As[bf_][(r_) * 64 + ((((q_)) ^ ((r_) & 7)) << 3)])
#define LDB8(bf_, r_, q_) (*(const short8*)&Bs[bf_][(r_) * 64 + ((((q_)) ^ ((r_) & 7)) << 3)])

#define MMA_T2(JB)                                                           \
    _Pragma("unroll")                                                        \
    for (int kk = 0; kk < 2; ++kk)                                           \
        _Pragma("unroll")                                                    \
        for (int mi = 0; mi < 4; ++mi)                                       \
            _Pragma("unroll")                                                \
            for (int nj = 0; nj < 2; ++nj)                                   \
                acc[mi][(JB) + nj] =                                         \
                    __builtin_amdgcn_mfma_f32_16x16x32_bf16(                 \
                        b[(JB) + nj][kk], a[mi][kk],                         \
                        acc[mi][(JB) + nj], 0, 0, 0);

#define KLOOP2(MM)                                                           \
    for (int kt = 0; kt < NT12; ++kt) {                                      \
        const int buf = kt & 1;                                              \
        /* ---- P1: all A frags (8) + b01 (4); stage B(kt+1) ---- */         \
        _Pragma("unroll")                                                    \
        for (int mi = 0; mi < 4; ++mi)                                       \
            _Pragma("unroll")                                                \
            for (int kk = 0; kk < 2; ++kk)                                   \
                a[mi][kk] = LDA8(buf, ar0 + mi * 16, quad + kk * 4);         \
        _Pragma("unroll")                                                    \
        for (int nj = 0; nj < 2; ++nj)                                       \
            _Pragma("unroll")                                                \
            for (int kk = 0; kk < 2; ++kk)                                   \
                b[nj][kk] = LDB8(buf, br0 + nj * 16, quad + kk * 4);         \
        if (kt + 1 < NT12) stage_B(kt + 1);                                  \
        BAR(); LGKM0(); SCHED0();                                            \
        PRIO1(); MM(0); PRIO0();                                             \
        BAR();                                                               \
        /* ---- P2: b23 (4); stage A(kt+2); counted wait ---- */             \
        _Pragma("unroll")                                                    \
        for (int nj = 2; nj < 4; ++nj)                                       \
            _Pragma("unroll")                                                \
            for (int kk = 0; kk < 2; ++kk)                                   \
                b[nj][kk] = LDB8(buf, br0 + nj * 16, quad + kk * 4);         \
        if (kt + 2 < NT12) stage_A(kt + 2);                                  \
        BAR(); LGKM0(); SCHED0();                                            \
        PRIO1(); MM(2); PRIO0();                                             \
        if (kt + 2 < NT12) {                                                 \
            if (wuni < 4) { VMC4(); } else { VMC0(); }                       \
        } else if (kt + 1 < NT12) { VMC0(); }                                \
        BAR();                                                               \
    }

__global__ __launch_bounds__(384, 3) void gemm_proj(
    const short* __restrict__ A, const short* __restrict__ Bt,
    const float* __restrict__ bias, float* __restrict__ Cout,
    int N, int nbx)
{
    __shared__ __align__(16) short As[2][128 * 64];   // 2 x 16 KB
    __shared__ __align__(16) short Bs[2][192 * 64];   // 2 x 24 KB  (total 80 KB)

    const int tid  = threadIdx.x;
    const int wave = tid >> 6;
    const int lane = tid & 63;
    const int ln15 = lane & 15;
    const int quad = lane >> 4;
    const int wm   = wave / 3;         // 0..1  (M, 64 rows each)
    const int wn   = wave % 3;         // 0..2  (N, 64 cols each)
    const int wuni = __builtin_amdgcn_readfirstlane(wave);  // uniform wave id

    // XCD-bijective swizzle: nwg = 64*nbx (divisible by 8); 8*nbx blocks/XCD
    const int orig = blockIdx.x;
    const int wg   = (orig & 7) * (8 * nbx) + (orig >> 3);
    const int bx   = wg % nbx;
    const int by   = wg / nbx;
    const int row0 = by * 128;
    const int col0 = bx * 192;

    const short* Ag = A  + (size_t)row0 * EMB;
    const short* Bg = Bt + (size_t)col0 * EMB;

    auto stage_A = [&](int t) {
        if (wave >= 4) return;
        const int buf = t & 1;
        #pragma unroll
        for (int p = 0; p < 4; ++p) {
            const int id  = (wave * 4 + p) * 64 + lane;  // 0..1023
            const int row = id >> 3;                     // 0..127
            const int c   = (id & 7) ^ (row & 7);
            async_load16(Ag + (size_t)row * EMB + t * 64 + c * 8, &As[buf][id * 8]);
        }
    };
    auto stage_B = [&](int t) {
        const int buf = t & 1;
        #pragma unroll
        for (int p = 0; p < 4; ++p) {
            const int id  = (wave * 4 + p) * 64 + lane;  // 0..1535
            const int row = id >> 3;                     // 0..191
            const int c   = (id & 7) ^ (row & 7);
            async_load16(Bg + (size_t)row * EMB + t * 64 + c * 8, &Bs[buf][id * 8]);
        }
    };

    floatx4 acc[4][4];
    #pragma unroll
    for (int i = 0; i < 4; ++i)
        #pragma unroll
        for (int j = 0; j < 4; ++j) acc[i][j] = (floatx4){0.f, 0.f, 0.f, 0.f};

    short8 a[4][2];
    short8 b[4][2];

    // ---- prologue: A(0), B(0), A(1); keep A(1) in flight ----
    stage_A(0); stage_B(0); stage_A(1);
    if (wuni < 4) { VMC4(); } else { VMC0(); }
    BAR();

    const int ar0 = wm * 64 + ln15;
    const int br0 = wn * 64 + ln15;

    KLOOP2(MMA_T2)

    // ---- epilogue: trans acc (lane holds row r=..+ln15, cols c=..+quad*4+reg) ----
    const int wr = wm * 64, wc = wn * 64;
    float4 b4[4];
    #pragma unroll
    for (int j = 0; j < 4; ++j)
        b4[j] = *(const float4*)&bias[col0 + wc + j * 16 + quad * 4];
    #pragma unroll
    for (int i = 0; i < 4; ++i) {
        const int r = row0 + wr + i * 16 + ln15;
        #pragma unroll
        for (int j = 0; j < 4; ++j) {
            const int c = col0 + wc + j * 16 + quad * 4;
            float4 v;
            v.x = acc[i][j][0] + b4[j].x;
            v.y = acc[i][j][1] + b4[j].y;
            v.z = acc[i][j][2] + b4[j].z;
            v.w = acc[i][j][3] + b4[j].w;
            *(float4*)&Cout[(size_t)r * N + c] = v;
        }
    }
}

// ---------------------------------------------------------------------------
// MFMA flash attention — QBLK=128 (8 waves), DOUBLE-BUFFERED K/V with ONE
// barrier per KV tile:
//   sync -> compute from buf[kt&1] -> ds_write regs(kt+1) into buf^1 ->
//   global-load regs(kt+2).
// Hazards: reads of buf^1 @ kt-1 precede sync(kt) which precedes writes of
// buf^1 @ kt; writes @ kt precede sync(kt+1) which precedes reads @ kt+1
// (__syncthreads drains lgkm). Ps roundtrip is wave-private (no barrier).
// Arithmetic and accumulation order identical to round 7 -> absmax unchanged.
// LDS 54 KB -> 2 blocks/CU.
// ---------------------------------------------------------------------------
#define LDK 72  // padded LDS row stride (shorts): 144 B

__global__ __launch_bounds__(512) void attn_mfma(
    const short* __restrict__ qkv, const short* __restrict__ vt,
    short* __restrict__ out)
{
    __shared__ __align__(16) short Ks[2][64 * LDK];  // K tiles  2 x 9 KB
    __shared__ __align__(16) short Vt[2][64 * LDK];  // V^T tiles 2 x 9 KB
    __shared__ __align__(16) short Ps[8 * 16 * LDK]; // per-wave P   18 KB

    const int tid  = threadIdx.x;
    const int wave = tid >> 6;        // 0..7
    const int lane = tid & 63;
    const int ln15 = lane & 15;
    const int quad = lane >> 4;

    const int qc = 7 - (int)(blockIdx.x / (BATCH * NH));   // 0..7, heavy first
    const int bh = blockIdx.x % (BATCH * NH);
    const int h  = bh % NH;
    const int b  = bh / NH;

    const int q0w = qc * 128 + wave * 16;   // this wave's first Q row

    const short* qkv_b = qkv + (size_t)b * SEQ * QKVW + h * HD;
    const short* Kg  = qkv_b + EMB;
    const short* Vtg = vt + ((size_t)b * EMB + h * HD) * SEQ;

    short8 qf[2];
    {
        const short* qrow = qkv_b + (size_t)(q0w + ln15) * QKVW;
        qf[0] = *(const short8*)(qrow + quad * 8);
        qf[1] = *(const short8*)(qrow + quad * 8 + 32);
    }

    floatx4 o[4];
    #pragma unroll
    for (int i = 0; i < 4; ++i) o[i] = (floatx4){0.f, 0.f, 0.f, 0.f};
    float lp[4] = {0.f, 0.f, 0.f, 0.f};   // per-lane l partials

    const int rr = tid >> 3;          // 0..63  (tile row / d index)
    const int c8 = (tid & 7) * 8;     // 0..56

    const int nkt = 2 * qc + 2;       // KV tiles (nkt >= 2 always)

    // ---- prologue: tile 0 -> regs -> buf0; tile 1 -> regs ----
    uint4 kreg = *(const uint4*)(Kg  + (size_t)rr * QKVW + c8);
    uint4 vreg = *(const uint4*)(Vtg + (size_t)rr * SEQ + c8);
    *(uint4*)&Ks[0][rr * LDK + c8] = kreg;
    *(uint4*)&Vt[0][rr * LDK + c8] = vreg;
    kreg = *(const uint4*)(Kg  + (size_t)(64 + rr) * QKVW + c8);
    vreg = *(const uint4*)(Vtg + (size_t)rr * SEQ + 64 + c8);

    for (int kt = 0; kt < nkt; ++kt) {
        const int cb = kt & 1;
        __syncthreads();   // buf[cb] fully written; buf[cb^1] reads (kt-1) done

        // ---- S = Q · K^T ----
        floatx4 s[4];
        #pragma unroll
        for (int i = 0; i < 4; ++i) s[i] = (floatx4){0.f, 0.f, 0.f, 0.f};
        #pragma unroll
        for (int st = 0; st < 2; ++st)
            #pragma unroll
            for (int sub = 0; sub < 4; ++sub) {
                const short8 kf = *(const short8*)&Ks[cb][(ln15 + sub * 16) * LDK + quad * 8 + st * 32];
                s[sub] = __builtin_amdgcn_mfma_f32_16x16x32_bf16(qf[st], kf, s[sub], 0, 0, 0);
            }

        // ---- P = exp(S/8), global causal mask, accumulate l ----
        #pragma unroll
        for (int sub = 0; sub < 4; ++sub)
            #pragma unroll
            for (int reg = 0; reg < 4; ++reg) {
                float pv = __expf(s[sub][reg] * 0.125f);
                if (kt * 64 + ln15 + sub * 16 > q0w + quad * 4 + reg) pv = 0.f;
                s[sub][reg] = pv;
            }
        #pragma unroll
        for (int reg = 0; reg < 4; ++reg)
            lp[reg] += (s[0][reg] + s[1][reg]) + (s[2][reg] + s[3][reg]);

        // ---- P (C-layout) -> swizzled LDS -> A-layout fragments (wave-private) ----
        short* Pw = &Ps[wave * 16 * LDK];
        #pragma unroll
        for (int sub = 0; sub < 4; ++sub)
            #pragma unroll
            for (int reg = 0; reg < 4; ++reg) {
                const int qr   = quad * 4 + reg;
                const int kr8  = sub * 2 + (ln15 >> 3);
                const int slot = (kr8 + 5 * quad + reg) & 7;
                Pw[qr * LDK + slot * 8 + (ln15 & 7)] = f2bf(s[sub][reg]);
            }

        short8 pf[2];
        #pragma unroll
        for (int st = 0; st < 2; ++st) {
            const int slot = ((quad + 4 * st) + 5 * (ln15 >> 2) + (ln15 & 3)) & 7;
            pf[st] = *(const short8*)&Pw[ln15 * LDK + slot * 8];
        }

        // ---- O += P · V ----
        #pragma unroll
        for (int st = 0; st < 2; ++st)
            #pragma unroll
            for (int sub = 0; sub < 4; ++sub) {
                const short8 vf = *(const short8*)&Vt[cb][(ln15 + sub * 16) * LDK + quad * 8 + st * 32];
                o[sub] = __builtin_amdgcn_mfma_f32_16x16x32_bf16(pf[st], vf, o[sub], 0, 0, 0);
            }

        // ---- write tile kt+1 regs -> buf^1; prefetch tile kt+2 -> regs ----
        if (kt + 1 < nkt) {
            *(uint4*)&Ks[cb ^ 1][rr * LDK + c8] = kreg;
            *(uint4*)&Vt[cb ^ 1][rr * LDK + c8] = vreg;
            if (kt + 2 < nkt) {
                kreg = *(const uint4*)(Kg  + (size_t)((kt + 2) * 64 + rr) * QKVW + c8);
                vreg = *(const uint4*)(Vtg + (size_t)rr * SEQ + (kt + 2) * 64 + c8);
            }
        }
    }

    // ---- epilogue: reduce l across the 16 lanes of each row, write O/l ----
    #pragma unroll
    for (int reg = 0; reg < 4; ++reg) {
        float t = lp[reg];
        #pragma unroll
        for (int off = 1; off <= 8; off <<= 1)
            t += __shfl_xor(t, off, 64);
        const float inv = 1.0f / t;
        const size_t row = (size_t)(b * SEQ + q0w + quad * 4 + reg) * EMB + h * HD;
        #pragma unroll
        for (int sub = 0; sub < 4; ++sub)
            out[row + ln15 + sub * 16] = f2bf(o[sub][reg] * inv);
    }
}

// ---------------------------------------------------------------------------
extern "C" void kernel_launch(void* const* d_in, const int* in_sizes, int n_in,
                              void* d_out, int out_size, void* d_ws, size_t ws_size,
                              hipStream_t stream)
{
    const float* x      = (const float*)d_in[0];   // [8,1024,768]
    const float* w_attn = (const float*)d_in[1];   // [768, 2304]
    const float* b_attn = (const float*)d_in[2];   // [2304]
    const float* w_proj = (const float*)d_in[3];   // [768, 768]
    const float* b_proj = (const float*)d_in[4];   // [768]
    float* out = (float*)d_out;                    // [8,1024,768] fp32

    const int M = BATCH * SEQ;       // 8192

    short* xb    = (short*)d_ws;                          // [8192, 768]
    short* waT   = xb    + (size_t)M * EMB;               // [2304, 768]
    short* wpT   = waT   + (size_t)QKVW * EMB;            // [768, 768]
    short* qkvb  = wpT   + (size_t)EMB * EMB;             // [8192, 2304] (V third unused)
    short* vtb   = qkvb  + (size_t)M * QKVW;              // [8, 768, 1024] V^T per head
    short* attnb = vtb   + (size_t)BATCH * EMB * SEQ;     // [8192, 768]

    // 0) fused conversions (1 launch instead of 3)
    prep<<<dim3(PREP_NB), dim3(256), 0, stream>>>(x, w_attn, w_proj, xb, waT, wpT);

    // 1) qkv = x @ w_attn + b_attn — 128^2 deep-lead kernel, 1152 blocks,
    //    2 blocks/CU (Q/K -> qkvb bf16, V -> vtb transposed).
    gemm_qkv_128<<<dim3((M / 128) * (QKVW / 128)), dim3(256), 0, stream>>>(
        xb, waT, b_attn, qkvb, vtb);

    // 2) causal MFMA flash attention — 128 Q rows/block, 8 waves,
    //    double-buffered K/V, one barrier per tile. 768 blocks x 512 threads.
    attn_mfma<<<dim3(8 * BATCH * NH), dim3(512), 0, stream>>>(qkvb, vtb, attnb);

    // 3) out = attn @ w_proj + b_proj — 128x192 pipelined kernel, grid 256,
    //    2 blocks/CU fully resident.
    gemm_proj<<<dim3((M / 128) * (EMB / 192)), dim3(384), 0, stream>>>(
        attnb, wpT, b_proj, out, EMB, EMB / 192);
}

// Round 10
// 179.631 us; speedup vs baseline: 1.1842x; 1.0500x over previous
//
#include <hip/hip_runtime.h>
#include <hip/hip_bf16.h>
#include <math.h>

// Problem constants (B=8, T=1024, EMB=768, H=12, D=64)
#define BATCH 8
#define SEQ   1024
#define EMB   768
#define NH    12
#define HD    64
#define QKVW  (3 * EMB)   // 2304
#define VOFF  (2 * EMB)   // 1536 — start of V columns in qkv

typedef short short8   __attribute__((ext_vector_type(8)));
typedef float floatx4  __attribute__((ext_vector_type(4)));

// fp32 -> bf16 (RNE) as raw short
__device__ __forceinline__ short f2bf(float f) {
    union { float f; unsigned u; } v; v.f = f;
    unsigned r = (v.u + 0x7fffu + ((v.u >> 16) & 1u)) >> 16;
    return (short)r;
}

// async 16B global -> LDS (wave-uniform base + lane*16 on the LDS side)
__device__ __forceinline__ void async_load16(const void* g, void* l) {
    __builtin_amdgcn_global_load_lds(
        (const __attribute__((address_space(1))) unsigned int*)g,
        (__attribute__((address_space(3))) unsigned int*)l, 16, 0, 0);
}

// ---------------------------------------------------------------------------
// Fused prep kernel (unchanged from round 8):
//   blocks [0,3072):        x fp32 -> xb bf16 (8 elems/thread)
//   blocks [3072,4800):     w_attn [768,2304] -> waT bf16 [2304,768]
//   blocks [4800,5376):     w_proj [768,768]  -> wpT bf16 [768,768]
// ---------------------------------------------------------------------------
#define CVT_NB 3072            // (8192*768/8)/256
#define TA_NB  1728            // (2304/32)*(768/32)
#define PREP_NB (CVT_NB + TA_NB + 576)

__global__ __launch_bounds__(256) void prep(
    const float* __restrict__ x, const float* __restrict__ w_attn,
    const float* __restrict__ w_proj, short* __restrict__ xb,
    short* __restrict__ waT, short* __restrict__ wpT)
{
    __shared__ float t[32][33];
    const int bid = blockIdx.x;
    const int tid = threadIdx.x;

    if (bid < CVT_NB) {
        const int i = bid * 256 + tid;
        const float4 a = ((const float4*)x)[2 * i];
        const float4 b = ((const float4*)x)[2 * i + 1];
        short8 s;
        s[0] = f2bf(a.x); s[1] = f2bf(a.y); s[2] = f2bf(a.z); s[3] = f2bf(a.w);
        s[4] = f2bf(b.x); s[5] = f2bf(b.y); s[6] = f2bf(b.z); s[7] = f2bf(b.w);
        ((short8*)xb)[i] = s;
        return;
    }

    const float* in; short* outT; int ncb, idx;
    if (bid < CVT_NB + TA_NB) { idx = bid - CVT_NB; in = w_attn; outT = waT; ncb = QKVW / 32; }
    else                      { idx = bid - CVT_NB - TA_NB; in = w_proj; outT = wpT; ncb = EMB / 32; }
    const int C  = ncb * 32;              // row width of input
    const int c0 = (idx % ncb) * 32;
    const int r0 = (idx / ncb) * 32;
    const int lx = tid & 31, ly = tid >> 5;
    #pragma unroll
    for (int i = 0; i < 32; i += 8)
        t[ly + i][lx] = in[(size_t)(r0 + ly + i) * C + c0 + lx];
    __syncthreads();
    #pragma unroll
    for (int i = 0; i < 32; i += 8)
        outT[(size_t)(c0 + ly + i) * EMB + r0 + lx] = f2bf(t[lx][ly + i]);
}

// ---------------------------------------------------------------------------
// Shared schedule macros
// ---------------------------------------------------------------------------
#define NT12 (EMB / 64)   // 12 K-tiles

#define BAR()    do { asm volatile("" ::: "memory"); __builtin_amdgcn_s_barrier(); \
                      asm volatile("" ::: "memory"); } while (0)
#define LGKM0()  asm volatile("s_waitcnt lgkmcnt(0)" ::: "memory")
#define VMC0()   asm volatile("s_waitcnt vmcnt(0)" ::: "memory")
#define VMC4()   asm volatile("s_waitcnt vmcnt(4)" ::: "memory")
#define SCHED0() __builtin_amdgcn_sched_barrier(0)
#define PRIO1()  __builtin_amdgcn_s_setprio(1)
#define PRIO0()  __builtin_amdgcn_s_setprio(0)

// swizzled fragment read: logical k-chunk q of row r lives at physical chunk q^(r&7)
#define LDA(bf_, r_, q_) (*(const short8*)&As[bf_][(r_) * 64 + ((((q_)) ^ ((r_) & 7)) << 3)])
#define LDB(bf_, r_, q_) (*(const short8*)&Bs[bf_][(r_) * 64 + ((((q_)) ^ ((r_) & 7)) << 3)])

// MFMAs over acc[0..3][JB..JB+NJ-1], kk-outer for independence.
// _T: trans path (C^T accumulate, mfma(b,a)); _D: direct (mfma(a,b)).
#define MMA_T(JB, NJ)                                                        \
    _Pragma("unroll")                                                        \
    for (int kk = 0; kk < 2; ++kk)                                           \
        _Pragma("unroll")                                                    \
        for (int mi = 0; mi < 4; ++mi)                                       \
            _Pragma("unroll")                                                \
            for (int nj = 0; nj < (NJ); ++nj)                                \
                acc[mi][(JB) + nj] =                                         \
                    __builtin_amdgcn_mfma_f32_16x16x32_bf16(                 \
                        b[(JB) + nj][kk], a[mi][kk],                         \
                        acc[mi][(JB) + nj], 0, 0, 0);

#define MMA_D(JB, NJ)                                                        \
    _Pragma("unroll")                                                        \
    for (int kk = 0; kk < 2; ++kk)                                           \
        _Pragma("unroll")                                                    \
        for (int mi = 0; mi < 4; ++mi)                                       \
            _Pragma("unroll")                                                \
            for (int nj = 0; nj < (NJ); ++nj)                                \
                acc[mi][(JB) + nj] =                                         \
                    __builtin_amdgcn_mfma_f32_16x16x32_bf16(                 \
                        a[mi][kk], b[(JB) + nj][kk],                         \
                        acc[mi][(JB) + nj], 0, 0, 0);

// ---------------------------------------------------------------------------
// QKV GEMM: 128x96 tile / BK=64 / 4 waves (2M x 2N), per-wave 64x48
// (acc[4][3]; same per-16x16 fragment+epilogue conventions as the verified
// 128^2 kernel). Grid = 64 x 24 = 1536 blocks = EXACTLY 3 fills of the 512
// resident slots (2 blocks/CU at 56 KB LDS) -> 0% tail quantization (the
// 128^2 grid of 1152 wasted 25% in a 3rd partial round).
// Same deep-lead 2-phase schedule (A lead 2 phases, B 1.5):
//   P1: read a0-3 + b01 of buf; stage B(kt+1)    [A-reads close at P1 bar]
//   P2: read b2 of buf; stage A(kt+2); VMC4      [leaves only A(kt+2) live]
// V boundary: 96 | 1536 -> col tiles 16..23 are V (clean vpath split).
// ---------------------------------------------------------------------------
#define QCW   96
#define QNBX  (QKVW / QCW)    // 24

#define KLOOPQ(MM)                                                           \
    for (int kt = 0; kt < NT12; ++kt) {                                      \
        const int buf = kt & 1;                                              \
        /* ---- P1: a0-3 (8 reads) + b01 (4 reads); stage B(kt+1) ---- */    \
        _Pragma("unroll")                                                    \
        for (int mi = 0; mi < 4; ++mi)                                       \
            _Pragma("unroll")                                                \
            for (int kk = 0; kk < 2; ++kk)                                   \
                a[mi][kk] = LDA(buf, ar0 + mi * 16, quad + kk * 4);          \
        _Pragma("unroll")                                                    \
        for (int nj = 0; nj < 2; ++nj)                                       \
            _Pragma("unroll")                                                \
            for (int kk = 0; kk < 2; ++kk)                                   \
                b[nj][kk] = LDB(buf, br0 + nj * 16, quad + kk * 4);          \
        if (kt + 1 < NT12) stage_B(kt + 1);                                  \
        BAR(); LGKM0(); SCHED0();                                            \
        PRIO1(); MM(0, 2); PRIO0();                                          \
        BAR();                                                               \
        /* ---- P2: b2 (2 reads); stage A(kt+2); counted wait ---- */        \
        _Pragma("unroll")                                                    \
        for (int kk = 0; kk < 2; ++kk)                                       \
            b[2][kk] = LDB(buf, br0 + 2 * 16, quad + kk * 4);                \
        if (kt + 2 < NT12) stage_A(kt + 2);                                  \
        BAR(); LGKM0(); SCHED0();                                            \
        PRIO1(); MM(2, 1); PRIO0();                                          \
        if (kt + 2 < NT12) { VMC4(); } else if (kt + 1 < NT12) { VMC0(); }   \
        BAR();                                                               \
    }

__global__ __launch_bounds__(256, 2) void gemm_qkv_96(
    const short* __restrict__ A, const short* __restrict__ Bt,
    const float* __restrict__ bias, short* __restrict__ qkvb,
    short* __restrict__ vt)
{
    __shared__ __align__(16) short As[2][128 * 64];   // 2 x 16 KB
    __shared__ __align__(16) short Bs[2][ 96 * 64];   // 2 x 12 KB (total 56 KB)

    const int tid  = threadIdx.x;
    const int wave = tid >> 6;         // 0..3
    const int lane = tid & 63;
    const int ln15 = lane & 15;
    const int quad = lane >> 4;
    const int wm   = wave >> 1;        // 0..1 (M, 64 rows each)
    const int wn   = wave & 1;         // 0..1 (N, 48 cols each)

    // XCD-bijective swizzle: 1536 blocks (1536 % 8 == 0), 192 per XCD.
    const int orig = blockIdx.x;
    const int wg   = (orig & 7) * 192 + (orig >> 3);
    const int bx   = wg % QNBX;           // 0..23
    const int by   = wg / QNBX;           // 0..63
    const int row0 = by * 128;
    const int col0 = bx * QCW;
    const bool vpath = (col0 >= VOFF);    // col tiles 16..23 are V columns

    const short* Ag = A  + (size_t)row0 * EMB;
    const short* Bg = Bt + (size_t)col0 * EMB;

    // staging, pre-swizzled global source (rule 21):
    // A: 128 rows = 1024 chunks, 4/thread.  B: 96 rows = 768 chunks, 3/thread.
    auto stage_A = [&](int t) {
        const int buf = t & 1;
        #pragma unroll
        for (int p = 0; p < 4; ++p) {
            const int id  = p * 256 + tid;        // 0..1023
            const int row = id >> 3;              // 0..127
            const int c   = (id & 7) ^ (row & 7);
            async_load16(Ag + (size_t)row * EMB + t * 64 + c * 8, &As[buf][id * 8]);
        }
    };
    auto stage_B = [&](int t) {
        const int buf = t & 1;
        #pragma unroll
        for (int p = 0; p < 3; ++p) {
            const int id  = p * 256 + tid;        // 0..767
            const int row = id >> 3;              // 0..95
            const int c   = (id & 7) ^ (row & 7);
            async_load16(Bg + (size_t)row * EMB + t * 64 + c * 8, &Bs[buf][id * 8]);
        }
    };

    floatx4 acc[4][3];
    #pragma unroll
    for (int i = 0; i < 4; ++i)
        #pragma unroll
        for (int j = 0; j < 3; ++j) acc[i][j] = (floatx4){0.f, 0.f, 0.f, 0.f};

    short8 a[4][2];
    short8 b[3][2];

    // ---- prologue: A(0)[4], B(0)[3], A(1)[4]; drain to 4 -> tile 0 ready,
    //      A(1) stays in flight ----
    stage_A(0); stage_B(0); stage_A(1);
    VMC4();
    BAR();

    const int ar0 = wm * 64 + ln15;
    const int br0 = wn * 48 + ln15;

    if (vpath) { KLOOPQ(MMA_D) } else { KLOOPQ(MMA_T) }

    // ---- epilogue (legacy per-16x16 conventions, per-wave 64x48) ----
    const int wr = wm * 64, wc = wn * 48;
    if (!vpath) {
        // trans acc: lane holds row r = ...+ln15, cols c = ...+quad*4+reg
        #pragma unroll
        for (int j = 0; j < 3; ++j) {
            const float4 b4 = *(const float4*)&bias[col0 + wc + j * 16 + quad * 4];
            #pragma unroll
            for (int i = 0; i < 4; ++i) {
                const int r = row0 + wr + i * 16 + ln15;
                const int c = col0 + wc + j * 16 + quad * 4;
                union { short s[4]; unsigned long long u; } pk;
                pk.s[0] = f2bf(acc[i][j][0] + b4.x);
                pk.s[1] = f2bf(acc[i][j][1] + b4.y);
                pk.s[2] = f2bf(acc[i][j][2] + b4.z);
                pk.s[3] = f2bf(acc[i][j][3] + b4.w);
                *(unsigned long long*)&qkvb[(size_t)r * QKVW + c] = pk.u;
            }
        }
    } else {
        // direct acc: lane holds col c = ...+ln15, rows r = ...+quad*4+reg
        #pragma unroll
        for (int j = 0; j < 3; ++j) {
            const int c  = col0 + wc + j * 16 + ln15;
            const float bv = bias[c];
            const int c2 = c - VOFF;
            #pragma unroll
            for (int i = 0; i < 4; ++i) {
                const int r = row0 + wr + i * 16 + quad * 4;
                union { short s[4]; unsigned long long u; } pk;
                #pragma unroll
                for (int reg = 0; reg < 4; ++reg)
                    pk.s[reg] = f2bf(acc[i][j][reg] + bv);
                *(unsigned long long*)&vt[(size_t)(r >> 10) * (EMB * SEQ) +
                                          (size_t)c2 * SEQ + (r & 1023)] = pk.u;
            }
        }
    }
}

// ---------------------------------------------------------------------------
// Proj GEMM: 128x192 tile / BK=64 / 6 waves (2M x 3N), per-wave 64x64.
// Unchanged.
// ---------------------------------------------------------------------------

#define LDA8(bf_, r_, q_) (*(const short8*)&As[bf_][(r_) * 64 + ((((q_)) ^ ((r_) & 7)) << 3)])
#define LDB8(bf_, r_, q_) (*(const short8*)&Bs[bf_][(r_) * 64 + ((((q_)) ^ ((r_) & 7)) << 3)])

#define MMA_T2(JB)                                                           \
    _Pragma("unroll")                                                        \
    for (int kk = 0; kk < 2; ++kk)                                           \
        _Pragma("unroll")                                                    \
        for (int mi = 0; mi < 4; ++mi)                                       \
            _Pragma("unroll")                                                \
            for (int nj = 0; nj < 2; ++nj)                                   \
                acc[mi][(JB) + nj] =                                         \
                    __builtin_amdgcn_mfma_f32_16x16x32_bf16(                 \
                        b[(JB) + nj][kk], a[mi][kk],                         \
                        acc[mi][(JB) + nj], 0, 0, 0);

#define KLOOP2(MM)                                                           \
    for (int kt = 0; kt < NT12; ++kt) {                                      \
        const int buf = kt & 1;                                              \
        /* ---- P1: all A frags (8) + b01 (4); stage B(kt+1) ---- */         \
        _Pragma("unroll")                                                    \
        for (int mi = 0; mi < 4; ++mi)                                       \
            _Pragma("unroll")                                                \
            for (int kk = 0; kk < 2; ++kk)                                   \
                a[mi][kk] = LDA8(buf, ar0 + mi * 16, quad + kk * 4);         \
        _Pragma("unroll")                                                    \
        for (int nj = 0; nj < 2; ++nj)                                       \
            _Pragma("unroll")                                                \
            for (int kk = 0; kk < 2; ++kk)                                   \
                b[nj][kk] = LDB8(buf, br0 + nj * 16, quad + kk * 4);         \
        if (kt + 1 < NT12) stage_B(kt + 1);                                  \
        BAR(); LGKM0(); SCHED0();                                            \
        PRIO1(); MM(0); PRIO0();                                             \
        BAR();                                                               \
        /* ---- P2: b23 (4); stage A(kt+2); counted wait ---- */             \
        _Pragma("unroll")                                                    \
        for (int nj = 2; nj < 4; ++nj)                                       \
            _Pragma("unroll")                                                \
            for (int kk = 0; kk < 2; ++kk)                                   \
                b[nj][kk] = LDB8(buf, br0 + nj * 16, quad + kk * 4);         \
        if (kt + 2 < NT12) stage_A(kt + 2);                                  \
        BAR(); LGKM0(); SCHED0();                                            \
        PRIO1(); MM(2); PRIO0();                                             \
        if (kt + 2 < NT12) {                                                 \
            if (wuni < 4) { VMC4(); } else { VMC0(); }                       \
        } else if (kt + 1 < NT12) { VMC0(); }                                \
        BAR();                                                               \
    }

__global__ __launch_bounds__(384, 3) void gemm_proj(
    const short* __restrict__ A, const short* __restrict__ Bt,
    const float* __restrict__ bias, float* __restrict__ Cout,
    int N, int nbx)
{
    __shared__ __align__(16) short As[2][128 * 64];   // 2 x 16 KB
    __shared__ __align__(16) short Bs[2][192 * 64];   // 2 x 24 KB  (total 80 KB)

    const int tid  = threadIdx.x;
    const int wave = tid >> 6;
    const int lane = tid & 63;
    const int ln15 = lane & 15;
    const int quad = lane >> 4;
    const int wm   = wave / 3;         // 0..1  (M, 64 rows each)
    const int wn   = wave % 3;         // 0..2  (N, 64 cols each)
    const int wuni = __builtin_amdgcn_readfirstlane(wave);  // uniform wave id

    // XCD-bijective swizzle: nwg = 64*nbx (divisible by 8); 8*nbx blocks/XCD
    const int orig = blockIdx.x;
    const int wg   = (orig & 7) * (8 * nbx) + (orig >> 3);
    const int bx   = wg % nbx;
    const int by   = wg / nbx;
    const int row0 = by * 128;
    const int col0 = bx * 192;

    const short* Ag = A  + (size_t)row0 * EMB;
    const short* Bg = Bt + (size_t)col0 * EMB;

    auto stage_A = [&](int t) {
        if (wave >= 4) return;
        const int buf = t & 1;
        #pragma unroll
        for (int p = 0; p < 4; ++p) {
            const int id  = (wave * 4 + p) * 64 + lane;  // 0..1023
            const int row = id >> 3;                     // 0..127
            const int c   = (id & 7) ^ (row & 7);
            async_load16(Ag + (size_t)row * EMB + t * 64 + c * 8, &As[buf][id * 8]);
        }
    };
    auto stage_B = [&](int t) {
        const int buf = t & 1;
        #pragma unroll
        for (int p = 0; p < 4; ++p) {
            const int id  = (wave * 4 + p) * 64 + lane;  // 0..1535
            const int row = id >> 3;                     // 0..191
            const int c   = (id & 7) ^ (row & 7);
            async_load16(Bg + (size_t)row * EMB + t * 64 + c * 8, &Bs[buf][id * 8]);
        }
    };

    floatx4 acc[4][4];
    #pragma unroll
    for (int i = 0; i < 4; ++i)
        #pragma unroll
        for (int j = 0; j < 4; ++j) acc[i][j] = (floatx4){0.f, 0.f, 0.f, 0.f};

    short8 a[4][2];
    short8 b[4][2];

    // ---- prologue: A(0), B(0), A(1); keep A(1) in flight ----
    stage_A(0); stage_B(0); stage_A(1);
    if (wuni < 4) { VMC4(); } else { VMC0(); }
    BAR();

    const int ar0 = wm * 64 + ln15;
    const int br0 = wn * 64 + ln15;

    KLOOP2(MMA_T2)

    // ---- epilogue: trans acc (lane holds row r=..+ln15, cols c=..+quad*4+reg) ----
    const int wr = wm * 64, wc = wn * 64;
    float4 b4[4];
    #pragma unroll
    for (int j = 0; j < 4; ++j)
        b4[j] = *(const float4*)&bias[col0 + wc + j * 16 + quad * 4];
    #pragma unroll
    for (int i = 0; i < 4; ++i) {
        const int r = row0 + wr + i * 16 + ln15;
        #pragma unroll
        for (int j = 0; j < 4; ++j) {
            const int c = col0 + wc + j * 16 + quad * 4;
            float4 v;
            v.x = acc[i][j][0] + b4[j].x;
            v.y = acc[i][j][1] + b4[j].y;
            v.z = acc[i][j][2] + b4[j].z;
            v.w = acc[i][j][3] + b4[j].w;
            *(float4*)&Cout[(size_t)r * N + c] = v;
        }
    }
}

// ---------------------------------------------------------------------------
// MFMA flash attention — QBLK=128 (8 waves), double-buffered K/V, one
// barrier per KV tile (round-9 verified, neutral vs r7 but kept). Unchanged.
// ---------------------------------------------------------------------------
#define LDK 72  // padded LDS row stride (shorts): 144 B

__global__ __launch_bounds__(512) void attn_mfma(
    const short* __restrict__ qkv, const short* __restrict__ vt,
    short* __restrict__ out)
{
    __shared__ __align__(16) short Ks[2][64 * LDK];  // K tiles  2 x 9 KB
    __shared__ __align__(16) short Vt[2][64 * LDK];  // V^T tiles 2 x 9 KB
    __shared__ __align__(16) short Ps[8 * 16 * LDK]; // per-wave P   18 KB

    const int tid  = threadIdx.x;
    const int wave = tid >> 6;        // 0..7
    const int lane = tid & 63;
    const int ln15 = lane & 15;
    const int quad = lane >> 4;

    const int qc = 7 - (int)(blockIdx.x / (BATCH * NH));   // 0..7, heavy first
    const int bh = blockIdx.x % (BATCH * NH);
    const int h  = bh % NH;
    const int b  = bh / NH;

    const int q0w = qc * 128 + wave * 16;   // this wave's first Q row

    const short* qkv_b = qkv + (size_t)b * SEQ * QKVW + h * HD;
    const short* Kg  = qkv_b + EMB;
    const short* Vtg = vt + ((size_t)b * EMB + h * HD) * SEQ;

    short8 qf[2];
    {
        const short* qrow = qkv_b + (size_t)(q0w + ln15) * QKVW;
        qf[0] = *(const short8*)(qrow + quad * 8);
        qf[1] = *(const short8*)(qrow + quad * 8 + 32);
    }

    floatx4 o[4];
    #pragma unroll
    for (int i = 0; i < 4; ++i) o[i] = (floatx4){0.f, 0.f, 0.f, 0.f};
    float lp[4] = {0.f, 0.f, 0.f, 0.f};   // per-lane l partials

    const int rr = tid >> 3;          // 0..63  (tile row / d index)
    const int c8 = (tid & 7) * 8;     // 0..56

    const int nkt = 2 * qc + 2;       // KV tiles (nkt >= 2 always)

    // ---- prologue: tile 0 -> regs -> buf0; tile 1 -> regs ----
    uint4 kreg = *(const uint4*)(Kg  + (size_t)rr * QKVW + c8);
    uint4 vreg = *(const uint4*)(Vtg + (size_t)rr * SEQ + c8);
    *(uint4*)&Ks[0][rr * LDK + c8] = kreg;
    *(uint4*)&Vt[0][rr * LDK + c8] = vreg;
    kreg = *(const uint4*)(Kg  + (size_t)(64 + rr) * QKVW + c8);
    vreg = *(const uint4*)(Vtg + (size_t)rr * SEQ + 64 + c8);

    for (int kt = 0; kt < nkt; ++kt) {
        const int cb = kt & 1;
        __syncthreads();   // buf[cb] fully written; buf[cb^1] reads (kt-1) done

        // ---- S = Q · K^T ----
        floatx4 s[4];
        #pragma unroll
        for (int i = 0; i < 4; ++i) s[i] = (floatx4){0.f, 0.f, 0.f, 0.f};
        #pragma unroll
        for (int st = 0; st < 2; ++st)
            #pragma unroll
            for (int sub = 0; sub < 4; ++sub) {
                const short8 kf = *(const short8*)&Ks[cb][(ln15 + sub * 16) * LDK + quad * 8 + st * 32];
                s[sub] = __builtin_amdgcn_mfma_f32_16x16x32_bf16(qf[st], kf, s[sub], 0, 0, 0);
            }

        // ---- P = exp(S/8), global causal mask, accumulate l ----
        #pragma unroll
        for (int sub = 0; sub < 4; ++sub)
            #pragma unroll
            for (int reg = 0; reg < 4; ++reg) {
                float pv = __expf(s[sub][reg] * 0.125f);
                if (kt * 64 + ln15 + sub * 16 > q0w + quad * 4 + reg) pv = 0.f;
                s[sub][reg] = pv;
            }
        #pragma unroll
        for (int reg = 0; reg < 4; ++reg)
            lp[reg] += (s[0][reg] + s[1][reg]) + (s[2][reg] + s[3][reg]);

        // ---- P (C-layout) -> swizzled LDS -> A-layout fragments (wave-private) ----
        short* Pw = &Ps[wave * 16 * LDK];
        #pragma unroll
        for (int sub = 0; sub < 4; ++sub)
            #pragma unroll
            for (int reg = 0; reg < 4; ++reg) {
                const int qr   = quad * 4 + reg;
                const int kr8  = sub * 2 + (ln15 >> 3);
                const int slot = (kr8 + 5 * quad + reg) & 7;
                Pw[qr * LDK + slot * 8 + (ln15 & 7)] = f2bf(s[sub][reg]);
            }

        short8 pf[2];
        #pragma unroll
        for (int st = 0; st < 2; ++st) {
            const int slot = ((quad + 4 * st) + 5 * (ln15 >> 2) + (ln15 & 3)) & 7;
            pf[st] = *(const short8*)&Pw[ln15 * LDK + slot * 8];
        }

        // ---- O += P · V ----
        #pragma unroll
        for (int st = 0; st < 2; ++st)
            #pragma unroll
            for (int sub = 0; sub < 4; ++sub) {
                const short8 vf = *(const short8*)&Vt[cb][(ln15 + sub * 16) * LDK + quad * 8 + st * 32];
                o[sub] = __builtin_amdgcn_mfma_f32_16x16x32_bf16(pf[st], vf, o[sub], 0, 0, 0);
            }

        // ---- write tile kt+1 regs -> buf^1; prefetch tile kt+2 -> regs ----
        if (kt + 1 < nkt) {
            *(uint4*)&Ks[cb ^ 1][rr * LDK + c8] = kreg;
            *(uint4*)&Vt[cb ^ 1][rr * LDK + c8] = vreg;
            if (kt + 2 < nkt) {
                kreg = *(const uint4*)(Kg  + (size_t)((kt + 2) * 64 + rr) * QKVW + c8);
                vreg = *(const uint4*)(Vtg + (size_t)rr * SEQ + (kt + 2) * 64 + c8);
            }
        }
    }

    // ---- epilogue: reduce l across the 16 lanes of each row, write O/l ----
    #pragma unroll
    for (int reg = 0; reg < 4; ++reg) {
        float t = lp[reg];
        #pragma unroll
        for (int off = 1; off <= 8; off <<= 1)
            t += __shfl_xor(t, off, 64);
        const float inv = 1.0f / t;
        const size_t row = (size_t)(b * SEQ + q0w + quad * 4 + reg) * EMB + h * HD;
        #pragma unroll
        for (int sub = 0; sub < 4; ++sub)
            out[row + ln15 + sub * 16] = f2bf(o[sub][reg] * inv);
    }
}

// ---------------------------------------------------------------------------
extern "C" void kernel_launch(void* const* d_in, const int* in_sizes, int n_in,
                              void* d_out, int out_size, void* d_ws, size_t ws_size,
                              hipStream_t stream)
{
    const float* x      = (const float*)d_in[0];   // [8,1024,768]
    const float* w_attn = (const float*)d_in[1];   // [768, 2304]
    const float* b_attn = (const float*)d_in[2];   // [2304]
    const float* w_proj = (const float*)d_in[3];   // [768, 768]
    const float* b_proj = (const float*)d_in[4];   // [768]
    float* out = (float*)d_out;                    // [8,1024,768] fp32

    const int M = BATCH * SEQ;       // 8192

    short* xb    = (short*)d_ws;                          // [8192, 768]
    short* waT   = xb    + (size_t)M * EMB;               // [2304, 768]
    short* wpT   = waT   + (size_t)QKVW * EMB;            // [768, 768]
    short* qkvb  = wpT   + (size_t)EMB * EMB;             // [8192, 2304] (V third unused)
    short* vtb   = qkvb  + (size_t)M * QKVW;              // [8, 768, 1024] V^T per head
    short* attnb = vtb   + (size_t)BATCH * EMB * SEQ;     // [8192, 768]

    // 0) fused conversions (1 launch)
    prep<<<dim3(PREP_NB), dim3(256), 0, stream>>>(x, w_attn, w_proj, xb, waT, wpT);

    // 1) qkv = x @ w_attn + b_attn — 128x96 deep-lead kernel, 1536 blocks
    //    = 3 exact fills at 2 blocks/CU (Q/K -> qkvb bf16, V -> vtb transposed).
    gemm_qkv_96<<<dim3((M / 128) * QNBX), dim3(256), 0, stream>>>(
        xb, waT, b_attn, qkvb, vtb);

    // 2) causal MFMA flash attention — 128 Q rows/block, 8 waves,
    //    double-buffered K/V, one barrier per tile. 768 blocks x 512 threads.
    attn_mfma<<<dim3(8 * BATCH * NH), dim3(512), 0, stream>>>(qkvb, vtb, attnb);

    // 3) out = attn @ w_proj + b_proj — 128x192 pipelined kernel, grid 256,
    //    2 blocks/CU fully resident.
    gemm_proj<<<dim3((M / 128) * (EMB / 192)), dim3(384), 0, stream>>>(
        attnb, wpT, b_proj, out, EMB, EMB / 192);
}